// Round 1
// baseline (8568.359 us; speedup 1.0000x reference)
//
#include <hip/hip_runtime.h>
#include <cstddef>
#include <cmath>
#include <utility>

#define B_ 16
#define LQ_ 300
#define D_ 256
#define NH_ 8
#define HD_ 32
#define FF_ 1024
#define NBIN_ 33
#define NC_ 80
#define SUMP_ 12
#define TOT_ (NH_*SUMP_)   // 96
#define STOT_ 8400
#define R_ (B_*LQ_)        // 4800
#define NLAYERS_ 6

// ---------------------------------------------------------------------------
// GEMM: C[M,N] = act(A[M,K] @ W[K,N] + bias [+ add])
// 64x64 tile, 256 threads, each thread 4x4, BK=16.
// ACT: 0 none, 1 relu, 2 silu, 3 sigmoid, 4 clip(-10,10)
// ---------------------------------------------------------------------------
template<int ACT>
__launch_bounds__(256)
__global__ void gemm_kernel(const float* __restrict__ A, const float* __restrict__ W,
                            const float* __restrict__ bias, const float* __restrict__ add,
                            float* __restrict__ C, int M, int N, int K) {
  __shared__ float As[16][65];
  __shared__ float Ws[16][65];
  const int bm = blockIdx.y * 64, bn = blockIdx.x * 64;
  const int tid = threadIdx.x;
  const int tm = (tid >> 4) << 2;   // 0..60
  const int tn = (tid & 15) << 2;   // 0..60
  float acc[4][4] = {};
  for (int k0 = 0; k0 < K; k0 += 16) {
    #pragma unroll
    for (int t = 0; t < 4; ++t) {
      int idx = tid + t * 256;
      int mm = idx >> 4, kk = idx & 15;
      int gm = bm + mm, gk = k0 + kk;
      As[kk][mm] = (gm < M && gk < K) ? A[(size_t)gm * K + gk] : 0.f;
      int kk2 = idx >> 6, nn = idx & 63;
      int gk2 = k0 + kk2, gn = bn + nn;
      Ws[kk2][nn] = (gk2 < K && gn < N) ? W[(size_t)gk2 * N + gn] : 0.f;
    }
    __syncthreads();
    #pragma unroll
    for (int kk = 0; kk < 16; ++kk) {
      float a0 = As[kk][tm], a1 = As[kk][tm+1], a2 = As[kk][tm+2], a3 = As[kk][tm+3];
      float w0 = Ws[kk][tn], w1 = Ws[kk][tn+1], w2 = Ws[kk][tn+2], w3 = Ws[kk][tn+3];
      acc[0][0] += a0*w0; acc[0][1] += a0*w1; acc[0][2] += a0*w2; acc[0][3] += a0*w3;
      acc[1][0] += a1*w0; acc[1][1] += a1*w1; acc[1][2] += a1*w2; acc[1][3] += a1*w3;
      acc[2][0] += a2*w0; acc[2][1] += a2*w1; acc[2][2] += a2*w2; acc[2][3] += a2*w3;
      acc[3][0] += a3*w0; acc[3][1] += a3*w1; acc[3][2] += a3*w2; acc[3][3] += a3*w3;
    }
    __syncthreads();
  }
  #pragma unroll
  for (int i = 0; i < 4; ++i) {
    int gm = bm + tm + i; if (gm >= M) continue;
    #pragma unroll
    for (int j = 0; j < 4; ++j) {
      int gn = bn + tn + j; if (gn >= N) continue;
      float v = acc[i][j] + bias[gn];
      if (add) v += add[(size_t)gm * N + gn];
      if (ACT == 1) v = fmaxf(v, 0.f);
      if (ACT == 2) v = v / (1.f + expf(-v));
      if (ACT == 3) v = 1.f / (1.f + expf(-v));
      if (ACT == 4) v = fminf(fmaxf(v, -10.f), 10.f);
      C[(size_t)gm * N + gn] = v;
    }
  }
}

// ---------------------------------------------------------------------------
// Fused add/gate + LayerNorm over D=256. One block (256 threads) per row.
// MODE 0: x=a+b ; MODE 1: x=clip(a+b,+-65504) ; MODE 2: x=g12[:,:D]*a+g12[:,D:]*b
// In-place safe: each thread touches only its own element of a/b/out.
// ---------------------------------------------------------------------------
template<int MODE>
__launch_bounds__(256)
__global__ void ln_kernel(float* __restrict__ out, const float* __restrict__ a,
                          const float* __restrict__ b, const float* __restrict__ g12,
                          const float* __restrict__ gamma, const float* __restrict__ beta) {
  const int row = blockIdx.x, c = threadIdx.x;
  const size_t off = (size_t)row * D_ + c;
  float x;
  if (MODE == 0) x = a[off] + b[off];
  else if (MODE == 1) { x = a[off] + b[off]; x = fminf(fmaxf(x, -65504.f), 65504.f); }
  else {
    float g1 = g12[(size_t)row * 2 * D_ + c];
    float g2 = g12[(size_t)row * 2 * D_ + D_ + c];
    x = g1 * a[off] + g2 * b[off];
  }
  __shared__ float red[8];
  float s = x;
  #pragma unroll
  for (int o = 32; o; o >>= 1) s += __shfl_down(s, o);
  if ((c & 63) == 0) red[c >> 6] = s;
  __syncthreads();
  float mu = (red[0] + red[1] + red[2] + red[3]) * (1.f / D_);
  float dd = x - mu;
  float s2 = dd * dd;
  #pragma unroll
  for (int o = 32; o; o >>= 1) s2 += __shfl_down(s2, o);
  if ((c & 63) == 0) red[4 + (c >> 6)] = s2;
  __syncthreads();
  float var = (red[4] + red[5] + red[6] + red[7]) * (1.f / D_);
  out[off] = dd * rsqrtf(var + 1e-5f) * gamma[c] + beta[c];
}

// ---------------------------------------------------------------------------
// Self-attention (fused, no SxS matrix). One 64-thread wave per (b,h,q).
// Q,K,V layout: [B,LQ,NH*HD]; O same.
// ---------------------------------------------------------------------------
__launch_bounds__(64)
__global__ void attn_kernel(const float* __restrict__ Q, const float* __restrict__ K,
                            const float* __restrict__ V, float* __restrict__ O) {
  const int blk = blockIdx.x;
  const int qi = blk % LQ_;
  const int bh = blk / LQ_;
  const int h = bh % NH_, b = bh / NH_;
  const int lane = threadIdx.x;
  __shared__ float qs[HD_];
  __shared__ float ps[LQ_];
  const size_t qoff = (size_t)(b * LQ_ + qi) * D_ + h * HD_;
  if (lane < HD_) qs[lane] = Q[qoff + lane];
  __syncthreads();
  const float scale = 0.17677669529663687f;  // 32^-0.5
  for (int k0 = lane; k0 < LQ_; k0 += 64) {
    const float* kp = K + (size_t)(b * LQ_ + k0) * D_ + h * HD_;
    float s = 0.f;
    #pragma unroll
    for (int d = 0; d < HD_; ++d) s += qs[d] * kp[d];
    ps[k0] = s * scale;
  }
  __syncthreads();
  float m = -1e30f;
  for (int k0 = lane; k0 < LQ_; k0 += 64) m = fmaxf(m, ps[k0]);
  #pragma unroll
  for (int o = 32; o; o >>= 1) m = fmaxf(m, __shfl_down(m, o));
  m = __shfl(m, 0);
  float sum = 0.f;
  for (int k0 = lane; k0 < LQ_; k0 += 64) { float e = expf(ps[k0] - m); ps[k0] = e; sum += e; }
  #pragma unroll
  for (int o = 32; o; o >>= 1) sum += __shfl_down(sum, o);
  sum = __shfl(sum, 0);
  const float inv = 1.f / sum;
  __syncthreads();
  if (lane < HD_) {
    float o = 0.f;
    const float* vp = V + (size_t)b * LQ_ * D_ + h * HD_ + lane;
    for (int k0 = 0; k0 < LQ_; ++k0) o += ps[k0] * vp[(size_t)k0 * D_];
    O[qoff + lane] = o * inv;
  }
}

// ---------------------------------------------------------------------------
// Deformable cross-attention sampling. One block per (b,q); thread = (h, c).
// Samples directly from `memory` [B,STOT,D] (value transpose folded into index).
// ---------------------------------------------------------------------------
__launch_bounds__(256)
__global__ void deform_kernel(const float* __restrict__ mem, const float* __restrict__ offs,
                              const float* __restrict__ awl, const float* __restrict__ refp,
                              float* __restrict__ t2) {
  const int row = blockIdx.x;          // b*LQ + q
  const int b = row / LQ_;
  const int tid = threadIdx.x;
  const int h = tid >> 5, c = tid & 31;
  const float rx = refp[row * 4 + 0], ry = refp[row * 4 + 1];
  const float rw = refp[row * 4 + 2], rh = refp[row * 4 + 3];
  const float* awp = awl + (size_t)row * TOT_ + h * SUMP_;
  float wv[SUMP_];
  float wmax = -1e30f;
  #pragma unroll
  for (int p = 0; p < SUMP_; ++p) { wv[p] = awp[p]; wmax = fmaxf(wmax, wv[p]); }
  float wsum = 0.f;
  #pragma unroll
  for (int p = 0; p < SUMP_; ++p) { wv[p] = expf(wv[p] - wmax); wsum += wv[p]; }
  const float winv = 1.f / wsum;
  const float* op = offs + (size_t)row * (TOT_ * 2) + h * (SUMP_ * 2);
  const float* mbase = mem + (size_t)b * STOT_ * D_ + h * HD_ + c;
  float acc = 0.f;
  #pragma unroll
  for (int p = 0; p < SUMP_; ++p) {
    const int lvl = p >> 2;
    const int Wl = (lvl == 0) ? 80 : ((lvl == 1) ? 40 : 20);
    const int Hl = Wl;
    const int s0 = (lvl == 0) ? 0 : ((lvl == 1) ? 6400 : 8000);
    // offset = offs * (1/npts=0.25) * ref_wh * OFFSET_SCALE(0.5)
    float lx = rx + op[2 * p]     * 0.125f * rw;
    float ly = ry + op[2 * p + 1] * 0.125f * rh;
    // grid = 2*loc-1 ; x = (g+1)*W/2 - 0.5 = loc*W - 0.5
    float x = lx * Wl - 0.5f, y = ly * Hl - 0.5f;
    float xf = floorf(x), yf = floorf(y);
    int x0 = (int)xf, y0 = (int)yf;
    float wx = x - xf, wy = y - yf;
    const float* mb = mbase + (size_t)s0 * D_;
    float v = 0.f;
    bool xv0 = (x0 >= 0) && (x0 < Wl), xv1 = (x0 + 1 >= 0) && (x0 + 1 < Wl);
    bool yv0 = (y0 >= 0) && (y0 < Hl), yv1 = (y0 + 1 >= 0) && (y0 + 1 < Hl);
    if (yv0) {
      if (xv0) v += (1.f - wx) * (1.f - wy) * mb[(size_t)(y0 * Wl + x0) * D_];
      if (xv1) v += wx * (1.f - wy) * mb[(size_t)(y0 * Wl + x0 + 1) * D_];
    }
    if (yv1) {
      if (xv0) v += (1.f - wx) * wy * mb[(size_t)((y0 + 1) * Wl + x0) * D_];
      if (xv1) v += wx * wy * mb[(size_t)((y0 + 1) * Wl + x0 + 1) * D_];
    }
    acc += wv[p] * winv * v;
  }
  t2[(size_t)row * D_ + h * HD_ + c] = acc;
}

// ---------------------------------------------------------------------------
// corners -> dist (softmax over 33 bins dot project) -> distance2bbox
// ---------------------------------------------------------------------------
__launch_bounds__(256)
__global__ void bbox_kernel(const float* __restrict__ corners, const float* __restrict__ refi,
                            float* __restrict__ inter) {
  int row = blockIdx.x * blockDim.x + threadIdx.x;
  if (row >= R_) return;
  float proj[NBIN_];
  proj[0] = -4.f; proj[16] = 0.f; proj[32] = 4.f;
  const float step = powf(3.f, 1.f / 15.f);   // (ub1+1)^(2/(REG_MAX-2))
  float pw = 1.f;
  for (int i = 1; i <= 15; ++i) { pw *= step; proj[16 + i] = pw - 1.f; proj[16 - i] = 1.f - pw; }
  float dist[4];
  for (int s = 0; s < 4; ++s) {
    const float* cp = corners + (size_t)row * (4 * NBIN_) + s * NBIN_;
    float m = -1e30f;
    for (int j = 0; j < NBIN_; ++j) m = fmaxf(m, cp[j]);
    float sum = 0.f, dot = 0.f;
    for (int j = 0; j < NBIN_; ++j) { float e = expf(cp[j] - m); sum += e; dot += e * proj[j]; }
    dist[s] = dot / sum;
  }
  float px = refi[row * 4], py = refi[row * 4 + 1];
  float qw = refi[row * 4 + 2] * 0.25f, qh = refi[row * 4 + 3] * 0.25f;
  float x1 = px - (2.f + dist[0]) * qw, y1 = py - (2.f + dist[1]) * qh;
  float x2 = px + (2.f + dist[2]) * qw, y2 = py + (2.f + dist[3]) * qh;
  inter[row * 4 + 0] = (x1 + x2) * 0.5f;
  inter[row * 4 + 1] = (y1 + y2) * 0.5f;
  inter[row * 4 + 2] = x2 - x1;
  inter[row * 4 + 3] = y2 - y1;
}

// ---------------------------------------------------------------------------
// LQE head + final output assembly. One 64-thread wave per (b,q).
// out[row, 0:4] = inter ; out[row, 4:84] = scores + mlp2(topk-stats)
// ---------------------------------------------------------------------------
__launch_bounds__(64)
__global__ void lqe_kernel(const float* __restrict__ scores, const float* __restrict__ corners,
                           const float* __restrict__ w1, const float* __restrict__ b1,
                           const float* __restrict__ w2, const float* __restrict__ b2,
                           const float* __restrict__ inter, float* __restrict__ out) {
  const int row = blockIdx.x;
  const int tid = threadIdx.x;
  __shared__ float stat[20];
  __shared__ float lqe_s;
  if (tid < 4) {
    const float* cp = corners + (size_t)row * (4 * NBIN_) + tid * NBIN_;
    float m = -1e30f;
    for (int j = 0; j < NBIN_; ++j) m = fmaxf(m, cp[j]);
    float e[NBIN_]; float sum = 0.f;
    for (int j = 0; j < NBIN_; ++j) { e[j] = expf(cp[j] - m); sum += e[j]; }
    float inv = 1.f / sum;
    float mean = 0.f;
    for (int t = 0; t < 4; ++t) {           // top-4 descending (values > 0)
      int bi = 0; float best = -1.f;
      for (int j = 0; j < NBIN_; ++j) if (e[j] > best) { best = e[j]; bi = j; }
      e[bi] = -2.f;
      float v = best * inv;
      stat[tid * 5 + t] = v; mean += v;
    }
    stat[tid * 5 + 4] = mean * 0.25f;
  }
  __syncthreads();
  float s = b1[tid];
  #pragma unroll
  for (int i = 0; i < 20; ++i) s += stat[i] * w1[i * 64 + tid];
  float hv = s / (1.f + expf(-s));
  float v = hv * w2[tid];
  #pragma unroll
  for (int o = 32; o; o >>= 1) v += __shfl_down(v, o);
  if (tid == 0) lqe_s = v + b2[0];
  __syncthreads();
  if (tid < 4) out[(size_t)row * 84 + tid] = inter[row * 4 + tid];
  for (int c = tid; c < NC_; c += 64)
    out[(size_t)row * 84 + 4 + c] = scores[(size_t)row * NC_ + c] + lqe_s;
}

// ---------------------------------------------------------------------------
// small elementwise kernels
// ---------------------------------------------------------------------------
__global__ void fill0_kernel(float* __restrict__ p, int n) {
  int i = blockIdx.x * 256 + threadIdx.x; if (i < n) p[i] = 0.f;
}
__global__ void add_kernel(float* __restrict__ c, const float* __restrict__ a,
                           const float* __restrict__ b, int n) {
  int i = blockIdx.x * 256 + threadIdx.x; if (i < n) c[i] = a[i] + b[i];
}
__global__ void sigmoid_kernel(float* __restrict__ d, const float* __restrict__ s, int n) {
  int i = blockIdx.x * 256 + threadIdx.x; if (i < n) d[i] = 1.f / (1.f + expf(-s[i]));
}
// ref_init = sigmoid(pre + inv_sigmoid(ref_pts))
__global__ void prebb_kernel(float* __restrict__ d, const float* __restrict__ pre,
                             const float* __restrict__ refp, int n) {
  int i = blockIdx.x * 256 + threadIdx.x;
  if (i < n) {
    float x = refp[i];
    x = fminf(fmaxf(x, 1e-5f), 1.f - 1e-5f);
    float is = logf(x) - log1pf(-x);
    d[i] = 1.f / (1.f + expf(-(pre[i] + is)));
  }
}
// cat[row, 0:256]=a ; cat[row, 256:512]=b
__global__ void concat_kernel(float* __restrict__ cat, const float* __restrict__ a,
                              const float* __restrict__ b, int n) {
  int i = blockIdx.x * 256 + threadIdx.x;
  if (i < n) {
    int r = i >> 9, c = i & 511;
    cat[i] = (c < D_) ? a[(size_t)r * D_ + c] : b[(size_t)r * D_ + (c - D_)];
  }
}

// ---------------------------------------------------------------------------
// host orchestration
// ---------------------------------------------------------------------------
static void launch_gemm(hipStream_t st, const float* A, const float* W, const float* bias,
                        const float* add, float* C, int M, int N, int K, int act) {
  dim3 g((N + 63) / 64, (M + 63) / 64), blk(256);
  switch (act) {
    case 0: gemm_kernel<0><<<g, blk, 0, st>>>(A, W, bias, add, C, M, N, K); break;
    case 1: gemm_kernel<1><<<g, blk, 0, st>>>(A, W, bias, add, C, M, N, K); break;
    case 2: gemm_kernel<2><<<g, blk, 0, st>>>(A, W, bias, add, C, M, N, K); break;
    case 3: gemm_kernel<3><<<g, blk, 0, st>>>(A, W, bias, add, C, M, N, K); break;
    case 4: gemm_kernel<4><<<g, blk, 0, st>>>(A, W, bias, add, C, M, N, K); break;
  }
}

static inline dim3 egrid(int n) { return dim3((n + 255) / 256); }

extern "C" void kernel_launch(void* const* d_in, const int* in_sizes, int n_in,
                              void* d_out, int out_size, void* d_ws, size_t ws_size,
                              hipStream_t stream) {
  const float* target     = (const float*)d_in[0];
  const float* ref_unact  = (const float*)d_in[1];
  const float* memory     = (const float*)d_in[2];
  const float* sa_qw = (const float*)d_in[3];  const float* sa_qb = (const float*)d_in[4];
  const float* sa_kw = (const float*)d_in[5];  const float* sa_kb = (const float*)d_in[6];
  const float* sa_vw = (const float*)d_in[7];  const float* sa_vb = (const float*)d_in[8];
  const float* sa_ow = (const float*)d_in[9];  const float* sa_ob = (const float*)d_in[10];
  const float* n1_g  = (const float*)d_in[11]; const float* n1_b  = (const float*)d_in[12];
  const float* off_w = (const float*)d_in[13]; const float* off_b = (const float*)d_in[14];
  const float* aw_w  = (const float*)d_in[15]; const float* aw_b  = (const float*)d_in[16];
  const float* gate_w= (const float*)d_in[17]; const float* gate_b= (const float*)d_in[18];
  const float* gn_g  = (const float*)d_in[19]; const float* gn_b  = (const float*)d_in[20];
  const float* ff1_w = (const float*)d_in[21]; const float* ff1_b = (const float*)d_in[22];
  const float* ff2_w = (const float*)d_in[23]; const float* ff2_b = (const float*)d_in[24];
  const float* n3_g  = (const float*)d_in[25]; const float* n3_b  = (const float*)d_in[26];
  const float* bb_w1 = (const float*)d_in[27]; const float* bb_b1 = (const float*)d_in[28];
  const float* bb_w2 = (const float*)d_in[29]; const float* bb_b2 = (const float*)d_in[30];
  const float* bb_w3 = (const float*)d_in[31]; const float* bb_b3 = (const float*)d_in[32];
  const float* sc_w  = (const float*)d_in[33]; const float* sc_b  = (const float*)d_in[34];
  const float* lqe_w1= (const float*)d_in[35]; const float* lqe_b1= (const float*)d_in[36];
  const float* lqe_w2= (const float*)d_in[37]; const float* lqe_b2= (const float*)d_in[38];
  const float* qp_w1 = (const float*)d_in[39]; const float* qp_b1 = (const float*)d_in[40];
  const float* qp_w2 = (const float*)d_in[41]; const float* qp_b2 = (const float*)d_in[42];
  const float* pb_w1 = (const float*)d_in[43]; const float* pb_b1 = (const float*)d_in[44];
  const float* pb_w2 = (const float*)d_in[45]; const float* pb_b2 = (const float*)d_in[46];
  const float* pb_w3 = (const float*)d_in[47]; const float* pb_b3 = (const float*)d_in[48];
  float* out = (float*)d_out;

  // ---- workspace layout (floats) ----
  float* ws = (float*)d_ws;
  size_t woff = 0;
  auto alloc = [&](size_t n) { float* p = ws + woff; woff += n; return p; };
  float* output   = alloc((size_t)R_ * D_);
  float* out_prev = alloc((size_t)R_ * D_);
  float* qp       = alloc((size_t)R_ * D_);
  float* bufA     = alloc((size_t)R_ * D_);
  float* qbuf     = alloc((size_t)R_ * D_);   // also: offs, pre_bb out, scores
  float* kbuf     = alloc((size_t)R_ * D_);   // also: aw logits
  float* vbuf     = alloc((size_t)R_ * D_);
  float* t2       = alloc((size_t)R_ * D_);
  float* h1       = alloc((size_t)R_ * D_);
  float* h2       = alloc((size_t)R_ * D_);
  float* big      = alloc((size_t)R_ * FF_);  // qp hidden (R*512) / cat+g12 / ffn hidden
  float* corners0 = alloc((size_t)R_ * 4 * NBIN_);
  float* corners1 = alloc((size_t)R_ * 4 * NBIN_);
  float* refA     = alloc((size_t)R_ * 4);
  float* refB     = alloc((size_t)R_ * 4);
  float* ref_init = alloc((size_t)R_ * 4);
  if (ws_size < woff * sizeof(float)) return;  // insufficient scratch: fail loudly

  float* c_prev = corners0; float* c_cur = corners1;
  float* ref_cur = refA;    float* ref_nxt = refB;
  float* g12 = big + (size_t)R_ * 512;

  // ---- init ----
  fill0_kernel<<<egrid(R_ * D_), 256, 0, stream>>>(out_prev, R_ * D_);
  fill0_kernel<<<egrid(R_ * 4 * NBIN_), 256, 0, stream>>>(c_prev, R_ * 4 * NBIN_);
  sigmoid_kernel<<<egrid(R_ * 4), 256, 0, stream>>>(ref_cur, ref_unact, R_ * 4);
  hipMemcpyAsync(output, target, (size_t)R_ * D_ * sizeof(float),
                 hipMemcpyDeviceToDevice, stream);

  for (int i = 0; i < NLAYERS_; ++i) {
    const float* qw = sa_qw + (size_t)i * D_ * D_;  const float* qb = sa_qb + (size_t)i * D_;
    const float* kw = sa_kw + (size_t)i * D_ * D_;  const float* kb = sa_kb + (size_t)i * D_;
    const float* vw = sa_vw + (size_t)i * D_ * D_;  const float* vb = sa_vb + (size_t)i * D_;
    const float* ow = sa_ow + (size_t)i * D_ * D_;  const float* ob = sa_ob + (size_t)i * D_;

    // qp = clip(mlp2(ref_pts), -10, 10)
    launch_gemm(stream, ref_cur, qp_w1, qp_b1, nullptr, big, R_, 512, 4, 2);
    launch_gemm(stream, big, qp_w2, qp_b2, nullptr, qp, R_, D_, 512, 4);

    // ---- self attention ----
    add_kernel<<<egrid(R_ * D_), 256, 0, stream>>>(bufA, output, qp, R_ * D_);  // q = output+qp
    launch_gemm(stream, bufA, qw, qb, nullptr, qbuf, R_, D_, D_, 0);
    launch_gemm(stream, bufA, kw, kb, nullptr, kbuf, R_, D_, D_, 0);
    launch_gemm(stream, output, vw, vb, nullptr, vbuf, R_, D_, D_, 0);
    attn_kernel<<<dim3(B_ * NH_ * LQ_), 64, 0, stream>>>(qbuf, kbuf, vbuf, t2);
    launch_gemm(stream, t2, ow, ob, nullptr, h1, R_, D_, D_, 0);
    ln_kernel<0><<<dim3(R_), 256, 0, stream>>>(output, output, h1, nullptr,
                                               n1_g + (size_t)i * D_, n1_b + (size_t)i * D_);

    // ---- deformable cross attention ----
    add_kernel<<<egrid(R_ * D_), 256, 0, stream>>>(bufA, output, qp, R_ * D_);  // qc
    launch_gemm(stream, bufA, off_w + (size_t)i * D_ * TOT_ * 2, off_b + (size_t)i * TOT_ * 2,
                nullptr, qbuf, R_, TOT_ * 2, D_, 0);
    launch_gemm(stream, bufA, aw_w + (size_t)i * D_ * TOT_, aw_b + (size_t)i * TOT_,
                nullptr, kbuf, R_, TOT_, D_, 0);
    deform_kernel<<<dim3(R_), 256, 0, stream>>>(memory, qbuf, kbuf, ref_cur, t2);

    // ---- gateway ----
    concat_kernel<<<egrid(R_ * 512), 256, 0, stream>>>(big, output, t2, R_ * 512);
    launch_gemm(stream, big, gate_w + (size_t)i * 512 * 512, gate_b + (size_t)i * 512,
                nullptr, g12, R_, 512, 512, 3);
    ln_kernel<2><<<dim3(R_), 256, 0, stream>>>(output, output, t2, g12,
                                               gn_g + (size_t)i * D_, gn_b + (size_t)i * D_);

    // ---- FFN ----
    launch_gemm(stream, output, ff1_w + (size_t)i * D_ * FF_, ff1_b + (size_t)i * FF_,
                nullptr, big, R_, FF_, D_, 1);
    launch_gemm(stream, big, ff2_w + (size_t)i * FF_ * D_, ff2_b + (size_t)i * D_,
                nullptr, t2, R_, D_, FF_, 0);
    ln_kernel<1><<<dim3(R_), 256, 0, stream>>>(output, output, t2, nullptr,
                                               n3_g + (size_t)i * D_, n3_b + (size_t)i * D_);

    // ---- FDR box refinement ----
    if (i == 0) {
      launch_gemm(stream, output, pb_w1, pb_b1, nullptr, h1, R_, D_, D_, 2);
      launch_gemm(stream, h1, pb_w2, pb_b2, nullptr, h2, R_, D_, D_, 2);
      launch_gemm(stream, h2, pb_w3, pb_b3, nullptr, qbuf, R_, 4, D_, 0);
      prebb_kernel<<<egrid(R_ * 4), 256, 0, stream>>>(ref_init, qbuf, ref_cur, R_ * 4);
    }
    add_kernel<<<egrid(R_ * D_), 256, 0, stream>>>(bufA, output, out_prev, R_ * D_);
    launch_gemm(stream, bufA, bb_w1 + (size_t)i * D_ * D_, bb_b1 + (size_t)i * D_,
                nullptr, h1, R_, D_, D_, 2);
    launch_gemm(stream, h1, bb_w2 + (size_t)i * D_ * D_, bb_b2 + (size_t)i * D_,
                nullptr, h2, R_, D_, D_, 2);
    launch_gemm(stream, h2, bb_w3 + (size_t)i * D_ * 4 * NBIN_, bb_b3 + (size_t)i * 4 * NBIN_,
                c_prev /*add*/, c_cur, R_, 4 * NBIN_, D_, 0);
    bbox_kernel<<<egrid(R_), 256, 0, stream>>>(c_cur, ref_init, ref_nxt);

    if (i == NLAYERS_ - 1) {
      launch_gemm(stream, output, sc_w + (size_t)i * D_ * NC_, sc_b + (size_t)i * NC_,
                  nullptr, qbuf, R_, NC_, D_, 0);
      lqe_kernel<<<dim3(R_), 64, 0, stream>>>(qbuf, c_cur,
                                              lqe_w1 + (size_t)i * 20 * 64, lqe_b1 + (size_t)i * 64,
                                              lqe_w2 + (size_t)i * 64, lqe_b2 + (size_t)i,
                                              ref_nxt, out);
    } else {
      hipMemcpyAsync(out_prev, output, (size_t)R_ * D_ * sizeof(float),
                     hipMemcpyDeviceToDevice, stream);
      std::swap(c_prev, c_cur);
      std::swap(ref_cur, ref_nxt);
    }
  }
}

// Round 2
// 2856.090 us; speedup vs baseline: 3.0000x; 3.0000x over previous
//
#include <hip/hip_runtime.h>
#include <cstddef>
#include <cmath>
#include <utility>

#define B_ 16
#define LQ_ 300
#define D_ 256
#define NH_ 8
#define HD_ 32
#define FF_ 1024
#define NBIN_ 33
#define NC_ 80
#define SUMP_ 12
#define TOT_ (NH_*SUMP_)   // 96
#define STOT_ 8400
#define R_ (B_*LQ_)        // 4800
#define NLAYERS_ 6

typedef short bf16x8 __attribute__((ext_vector_type(8)));
typedef float f32x4  __attribute__((ext_vector_type(4)));

static __device__ __forceinline__ short f2bf(float x) {
  union { float f; unsigned u; } v; v.f = x;
  unsigned r = v.u + 0x7fffu + ((v.u >> 16) & 1u);   // RNE
  return (short)(r >> 16);
}

// ---------------------------------------------------------------------------
// Weight convert+transpose: W [K,N] fp32 -> Wt [N,K] bf16. blockIdx.z = layer.
// ---------------------------------------------------------------------------
__launch_bounds__(256)
__global__ void wconv_kernel(const float* __restrict__ W, short* __restrict__ Wt,
                             int K, int N) {
  __shared__ float t[32][33];
  const size_t lo = (size_t)blockIdx.z * K * N;
  const float* Wl = W + lo;
  short* Wtl = Wt + lo;
  int k0 = blockIdx.x * 32, n0 = blockIdx.y * 32;
  int tr = threadIdx.x >> 5, tc = threadIdx.x & 31;
  #pragma unroll
  for (int i = 0; i < 4; ++i) {
    int k = k0 + tr + i * 8, n = n0 + tc;
    t[tr + i * 8][tc] = (k < K && n < N) ? Wl[(size_t)k * N + n] : 0.f;
  }
  __syncthreads();
  #pragma unroll
  for (int i = 0; i < 4; ++i) {
    int n = n0 + tr + i * 8, k = k0 + tc;
    if (n < N && k < K) Wtl[(size_t)n * K + k] = f2bf(t[tc][tr + i * 8]);
  }
}

// ---------------------------------------------------------------------------
// MFMA GEMM: C[M,N] = act(Astage @ Wt^T + bias [+ Cadd])
//   Astage[m,k] = (k < KA or no Acat ? A[m,k] : Acat[m,k-KA]) (+ Aadd[m,k])
//   A fp32 (converted to bf16 in staging), Wt bf16 [N,K].
// Block 256 thr (4 waves), tile 64x64, BK=32, wave tile 32x32 (4 mfma 16x16x32).
// Requires: M % 64 == 0, K % 32 == 0 (KA % 32 == 0 when Acat). N arbitrary.
// ACT: 0 none, 1 relu, 2 silu, 3 sigmoid, 4 clip(-10,10)
// ---------------------------------------------------------------------------
template<int ACT>
__launch_bounds__(256)
__global__ void mfma_gemm(const float* __restrict__ A, const float* __restrict__ Aadd,
                          const float* __restrict__ Acat, int KA,
                          const short* __restrict__ Wt, const float* __restrict__ bias,
                          const float* __restrict__ Cadd, float* __restrict__ C,
                          int M, int N, int K) {
  __shared__ short Abf[64][40];
  __shared__ short Wbf[64][40];
  const int bm = blockIdx.y * 64, bn = blockIdx.x * 64;
  const int tid = threadIdx.x;
  const int wid = tid >> 6, lane = tid & 63;
  const int wm = (wid >> 1) * 32, wn = (wid & 1) * 32;
  const int lr = lane & 15, lq = lane >> 4;
  const int lda = Acat ? KA : K;
  const int ldb = K - KA;

  f32x4 acc[2][2];
  #pragma unroll
  for (int i = 0; i < 2; ++i)
    #pragma unroll
    for (int j = 0; j < 2; ++j) acc[i][j] = (f32x4){0.f, 0.f, 0.f, 0.f};

  for (int k0 = 0; k0 < K; k0 += 32) {
    // --- stage A (fp32 -> bf16): 64 x 32 ---
    #pragma unroll
    for (int t = 0; t < 2; ++t) {
      int idx = tid + t * 256;
      int ar = idx >> 3, ak = (idx & 7) * 4;
      int gm = bm + ar, gk = k0 + ak;
      float4 v;
      if (Acat && gk >= KA) v = *(const float4*)(Acat + (size_t)gm * ldb + (gk - KA));
      else                  v = *(const float4*)(A + (size_t)gm * lda + gk);
      if (Aadd) {
        float4 w = *(const float4*)(Aadd + (size_t)gm * lda + gk);
        v.x += w.x; v.y += w.y; v.z += w.z; v.w += w.w;
      }
      short4 s; s.x = f2bf(v.x); s.y = f2bf(v.y); s.z = f2bf(v.z); s.w = f2bf(v.w);
      *(short4*)&Abf[ar][ak] = s;
    }
    // --- stage Wt (already bf16): 64 n-rows x 32 k ---
    {
      int wr = tid >> 2, wk = (tid & 3) * 8;
      int gn = bn + wr;
      bf16x8 wv;
      if (gn < N) wv = *(const bf16x8*)(Wt + (size_t)gn * K + k0 + wk);
      else        wv = (bf16x8){0, 0, 0, 0, 0, 0, 0, 0};
      *(bf16x8*)&Wbf[wr][wk] = wv;
    }
    __syncthreads();
    bf16x8 af0 = *(const bf16x8*)&Abf[wm + lr][lq * 8];
    bf16x8 af1 = *(const bf16x8*)&Abf[wm + 16 + lr][lq * 8];
    bf16x8 bf0 = *(const bf16x8*)&Wbf[wn + lr][lq * 8];
    bf16x8 bf1 = *(const bf16x8*)&Wbf[wn + 16 + lr][lq * 8];
    acc[0][0] = __builtin_amdgcn_mfma_f32_16x16x32_bf16(af0, bf0, acc[0][0], 0, 0, 0);
    acc[0][1] = __builtin_amdgcn_mfma_f32_16x16x32_bf16(af0, bf1, acc[0][1], 0, 0, 0);
    acc[1][0] = __builtin_amdgcn_mfma_f32_16x16x32_bf16(af1, bf0, acc[1][0], 0, 0, 0);
    acc[1][1] = __builtin_amdgcn_mfma_f32_16x16x32_bf16(af1, bf1, acc[1][1], 0, 0, 0);
    __syncthreads();
  }
  // --- epilogue: D row=(lq*4+r), col=lr within each 16x16 tile ---
  #pragma unroll
  for (int ti = 0; ti < 2; ++ti)
    #pragma unroll
    for (int tj = 0; tj < 2; ++tj)
      #pragma unroll
      for (int r = 0; r < 4; ++r) {
        int gm = bm + wm + ti * 16 + lq * 4 + r;
        int gn = bn + wn + tj * 16 + lr;
        if (gn >= N) continue;
        float v = acc[ti][tj][r] + bias[gn];
        if (Cadd) v += Cadd[(size_t)gm * N + gn];
        if (ACT == 1) v = fmaxf(v, 0.f);
        if (ACT == 2) v = v / (1.f + __expf(-v));
        if (ACT == 3) v = 1.f / (1.f + __expf(-v));
        if (ACT == 4) v = fminf(fmaxf(v, -10.f), 10.f);
        C[(size_t)gm * N + gn] = v;
      }
}

// ---------------------------------------------------------------------------
// Fallback fp32 GEMM (tiny shapes: qp1 K=4, pb3 N=4).
// ---------------------------------------------------------------------------
template<int ACT>
__launch_bounds__(256)
__global__ void gemm_kernel(const float* __restrict__ A, const float* __restrict__ W,
                            const float* __restrict__ bias, const float* __restrict__ add,
                            float* __restrict__ C, int M, int N, int K) {
  __shared__ float As[16][65];
  __shared__ float Ws[16][65];
  const int bm = blockIdx.y * 64, bn = blockIdx.x * 64;
  const int tid = threadIdx.x;
  const int tm = (tid >> 4) << 2;
  const int tn = (tid & 15) << 2;
  float acc[4][4] = {};
  for (int k0 = 0; k0 < K; k0 += 16) {
    #pragma unroll
    for (int t = 0; t < 4; ++t) {
      int idx = tid + t * 256;
      int mm = idx >> 4, kk = idx & 15;
      int gm = bm + mm, gk = k0 + kk;
      As[kk][mm] = (gm < M && gk < K) ? A[(size_t)gm * K + gk] : 0.f;
      int kk2 = idx >> 6, nn = idx & 63;
      int gk2 = k0 + kk2, gn = bn + nn;
      Ws[kk2][nn] = (gk2 < K && gn < N) ? W[(size_t)gk2 * N + gn] : 0.f;
    }
    __syncthreads();
    #pragma unroll
    for (int kk = 0; kk < 16; ++kk) {
      float a0 = As[kk][tm], a1 = As[kk][tm+1], a2 = As[kk][tm+2], a3 = As[kk][tm+3];
      float w0 = Ws[kk][tn], w1 = Ws[kk][tn+1], w2 = Ws[kk][tn+2], w3 = Ws[kk][tn+3];
      acc[0][0] += a0*w0; acc[0][1] += a0*w1; acc[0][2] += a0*w2; acc[0][3] += a0*w3;
      acc[1][0] += a1*w0; acc[1][1] += a1*w1; acc[1][2] += a1*w2; acc[1][3] += a1*w3;
      acc[2][0] += a2*w0; acc[2][1] += a2*w1; acc[2][2] += a2*w2; acc[2][3] += a2*w3;
      acc[3][0] += a3*w0; acc[3][1] += a3*w1; acc[3][2] += a3*w2; acc[3][3] += a3*w3;
    }
    __syncthreads();
  }
  #pragma unroll
  for (int i = 0; i < 4; ++i) {
    int gm = bm + tm + i; if (gm >= M) continue;
    #pragma unroll
    for (int j = 0; j < 4; ++j) {
      int gn = bn + tn + j; if (gn >= N) continue;
      float v = acc[i][j] + bias[gn];
      if (add) v += add[(size_t)gm * N + gn];
      if (ACT == 1) v = fmaxf(v, 0.f);
      if (ACT == 2) v = v / (1.f + __expf(-v));
      if (ACT == 3) v = 1.f / (1.f + __expf(-v));
      if (ACT == 4) v = fminf(fmaxf(v, -10.f), 10.f);
      C[(size_t)gm * N + gn] = v;
    }
  }
}

// ---------------------------------------------------------------------------
// LayerNorm (fused add/gate) over D=256. One block per row.
// ---------------------------------------------------------------------------
template<int MODE>
__launch_bounds__(256)
__global__ void ln_kernel(float* __restrict__ out, const float* __restrict__ a,
                          const float* __restrict__ b, const float* __restrict__ g12,
                          const float* __restrict__ gamma, const float* __restrict__ beta) {
  const int row = blockIdx.x, c = threadIdx.x;
  const size_t off = (size_t)row * D_ + c;
  float x;
  if (MODE == 0) x = a[off] + b[off];
  else if (MODE == 1) { x = a[off] + b[off]; x = fminf(fmaxf(x, -65504.f), 65504.f); }
  else {
    float g1 = g12[(size_t)row * 2 * D_ + c];
    float g2 = g12[(size_t)row * 2 * D_ + D_ + c];
    x = g1 * a[off] + g2 * b[off];
  }
  __shared__ float red[8];
  float s = x;
  #pragma unroll
  for (int o = 32; o; o >>= 1) s += __shfl_down(s, o);
  if ((c & 63) == 0) red[c >> 6] = s;
  __syncthreads();
  float mu = (red[0] + red[1] + red[2] + red[3]) * (1.f / D_);
  float dd = x - mu;
  float s2 = dd * dd;
  #pragma unroll
  for (int o = 32; o; o >>= 1) s2 += __shfl_down(s2, o);
  if ((c & 63) == 0) red[4 + (c >> 6)] = s2;
  __syncthreads();
  float var = (red[4] + red[5] + red[6] + red[7]) * (1.f / D_);
  out[off] = dd * rsqrtf(var + 1e-5f) * gamma[c] + beta[c];
}

// ---------------------------------------------------------------------------
// Self-attention v2: block per (b,h,half). K/V staged to LDS (broadcast reads),
// one query per thread, online-softmax two-pass.
// ---------------------------------------------------------------------------
__launch_bounds__(192)
__global__ void attn2_kernel(const float* __restrict__ Q, const float* __restrict__ K,
                             const float* __restrict__ V, float* __restrict__ O) {
  __shared__ float ks[LQ_][HD_];
  __shared__ float vs[LQ_][HD_];
  const int bh = blockIdx.x >> 1, half = blockIdx.x & 1;
  const int h = bh & 7, b = bh >> 3;
  const int tid = threadIdx.x;
  const float* Kb = K + (size_t)b * LQ_ * D_ + h * HD_;
  const float* Vb = V + (size_t)b * LQ_ * D_ + h * HD_;
  for (int idx = tid; idx < LQ_ * 8; idx += 192) {
    int row = idx >> 3, c = (idx & 7) * 4;
    *(float4*)&ks[row][c] = *(const float4*)(Kb + (size_t)row * D_ + c);
    *(float4*)&vs[row][c] = *(const float4*)(Vb + (size_t)row * D_ + c);
  }
  __syncthreads();
  if (tid >= 150) return;
  const int qi = half * 150 + tid;
  const float scale = 0.17677669529663687f;  // 32^-0.5
  float qv[HD_];
  const float* Qp = Q + (size_t)(b * LQ_ + qi) * D_ + h * HD_;
  #pragma unroll
  for (int d = 0; d < HD_; ++d) qv[d] = Qp[d] * scale;
  // pass 1: running max + denom
  float m = -1e30f, l = 0.f;
  for (int k = 0; k < LQ_; ++k) {
    float s = 0.f;
    #pragma unroll
    for (int d = 0; d < HD_; ++d) s += qv[d] * ks[k][d];
    if (s > m) { l *= __expf(m - s); m = s; }
    l += __expf(s - m);
  }
  const float inv = 1.f / l;
  // pass 2: accumulate P@V
  float o[HD_];
  #pragma unroll
  for (int d = 0; d < HD_; ++d) o[d] = 0.f;
  for (int k = 0; k < LQ_; ++k) {
    float s = 0.f;
    #pragma unroll
    for (int d = 0; d < HD_; ++d) s += qv[d] * ks[k][d];
    float p = __expf(s - m);
    #pragma unroll
    for (int d = 0; d < HD_; ++d) o[d] += p * vs[k][d];
  }
  float* Op = O + (size_t)(b * LQ_ + qi) * D_ + h * HD_;
  #pragma unroll
  for (int d4 = 0; d4 < 8; ++d4) {
    float4 v; v.x = o[d4*4] * inv; v.y = o[d4*4+1] * inv;
    v.z = o[d4*4+2] * inv; v.w = o[d4*4+3] * inv;
    *(float4*)(Op + d4 * 4) = v;
  }
}

// ---------------------------------------------------------------------------
// Deformable cross-attention sampling (unchanged from R0).
// ---------------------------------------------------------------------------
__launch_bounds__(256)
__global__ void deform_kernel(const float* __restrict__ mem, const float* __restrict__ offs,
                              const float* __restrict__ awl, const float* __restrict__ refp,
                              float* __restrict__ t2) {
  const int row = blockIdx.x;
  const int b = row / LQ_;
  const int tid = threadIdx.x;
  const int h = tid >> 5, c = tid & 31;
  const float rx = refp[row * 4 + 0], ry = refp[row * 4 + 1];
  const float rw = refp[row * 4 + 2], rh = refp[row * 4 + 3];
  const float* awp = awl + (size_t)row * TOT_ + h * SUMP_;
  float wv[SUMP_];
  float wmax = -1e30f;
  #pragma unroll
  for (int p = 0; p < SUMP_; ++p) { wv[p] = awp[p]; wmax = fmaxf(wmax, wv[p]); }
  float wsum = 0.f;
  #pragma unroll
  for (int p = 0; p < SUMP_; ++p) { wv[p] = __expf(wv[p] - wmax); wsum += wv[p]; }
  const float winv = 1.f / wsum;
  const float* op = offs + (size_t)row * (TOT_ * 2) + h * (SUMP_ * 2);
  const float* mbase = mem + (size_t)b * STOT_ * D_ + h * HD_ + c;
  float acc = 0.f;
  #pragma unroll
  for (int p = 0; p < SUMP_; ++p) {
    const int lvl = p >> 2;
    const int Wl = (lvl == 0) ? 80 : ((lvl == 1) ? 40 : 20);
    const int Hl = Wl;
    const int s0 = (lvl == 0) ? 0 : ((lvl == 1) ? 6400 : 8000);
    float lx = rx + op[2 * p]     * 0.125f * rw;
    float ly = ry + op[2 * p + 1] * 0.125f * rh;
    float x = lx * Wl - 0.5f, y = ly * Hl - 0.5f;
    float xf = floorf(x), yf = floorf(y);
    int x0 = (int)xf, y0 = (int)yf;
    float wx = x - xf, wy = y - yf;
    const float* mb = mbase + (size_t)s0 * D_;
    float v = 0.f;
    bool xv0 = (x0 >= 0) && (x0 < Wl), xv1 = (x0 + 1 >= 0) && (x0 + 1 < Wl);
    bool yv0 = (y0 >= 0) && (y0 < Hl), yv1 = (y0 + 1 >= 0) && (y0 + 1 < Hl);
    if (yv0) {
      if (xv0) v += (1.f - wx) * (1.f - wy) * mb[(size_t)(y0 * Wl + x0) * D_];
      if (xv1) v += wx * (1.f - wy) * mb[(size_t)(y0 * Wl + x0 + 1) * D_];
    }
    if (yv1) {
      if (xv0) v += (1.f - wx) * wy * mb[(size_t)((y0 + 1) * Wl + x0) * D_];
      if (xv1) v += wx * wy * mb[(size_t)((y0 + 1) * Wl + x0 + 1) * D_];
    }
    acc += wv[p] * winv * v;
  }
  t2[(size_t)row * D_ + h * HD_ + c] = acc;
}

// ---------------------------------------------------------------------------
// corners -> dist -> distance2bbox
// ---------------------------------------------------------------------------
__launch_bounds__(256)
__global__ void bbox_kernel(const float* __restrict__ corners, const float* __restrict__ refi,
                            float* __restrict__ inter) {
  int row = blockIdx.x * blockDim.x + threadIdx.x;
  if (row >= R_) return;
  float proj[NBIN_];
  proj[0] = -4.f; proj[16] = 0.f; proj[32] = 4.f;
  const float step = powf(3.f, 1.f / 15.f);
  float pw = 1.f;
  for (int i = 1; i <= 15; ++i) { pw *= step; proj[16 + i] = pw - 1.f; proj[16 - i] = 1.f - pw; }
  float dist[4];
  for (int s = 0; s < 4; ++s) {
    const float* cp = corners + (size_t)row * (4 * NBIN_) + s * NBIN_;
    float m = -1e30f;
    for (int j = 0; j < NBIN_; ++j) m = fmaxf(m, cp[j]);
    float sum = 0.f, dot = 0.f;
    for (int j = 0; j < NBIN_; ++j) { float e = __expf(cp[j] - m); sum += e; dot += e * proj[j]; }
    dist[s] = dot / sum;
  }
  float px = refi[row * 4], py = refi[row * 4 + 1];
  float qw = refi[row * 4 + 2] * 0.25f, qh = refi[row * 4 + 3] * 0.25f;
  float x1 = px - (2.f + dist[0]) * qw, y1 = py - (2.f + dist[1]) * qh;
  float x2 = px + (2.f + dist[2]) * qw, y2 = py + (2.f + dist[3]) * qh;
  inter[row * 4 + 0] = (x1 + x2) * 0.5f;
  inter[row * 4 + 1] = (y1 + y2) * 0.5f;
  inter[row * 4 + 2] = x2 - x1;
  inter[row * 4 + 3] = y2 - y1;
}

// ---------------------------------------------------------------------------
// LQE head + final output assembly.
// ---------------------------------------------------------------------------
__launch_bounds__(64)
__global__ void lqe_kernel(const float* __restrict__ scores, const float* __restrict__ corners,
                           const float* __restrict__ w1, const float* __restrict__ b1,
                           const float* __restrict__ w2, const float* __restrict__ b2,
                           const float* __restrict__ inter, float* __restrict__ out) {
  const int row = blockIdx.x;
  const int tid = threadIdx.x;
  __shared__ float stat[20];
  __shared__ float lqe_s;
  if (tid < 4) {
    const float* cp = corners + (size_t)row * (4 * NBIN_) + tid * NBIN_;
    float m = -1e30f;
    for (int j = 0; j < NBIN_; ++j) m = fmaxf(m, cp[j]);
    float e[NBIN_]; float sum = 0.f;
    for (int j = 0; j < NBIN_; ++j) { e[j] = __expf(cp[j] - m); sum += e[j]; }
    float inv = 1.f / sum;
    float mean = 0.f;
    for (int t = 0; t < 4; ++t) {
      int bi = 0; float best = -1.f;
      for (int j = 0; j < NBIN_; ++j) if (e[j] > best) { best = e[j]; bi = j; }
      e[bi] = -2.f;
      float v = best * inv;
      stat[tid * 5 + t] = v; mean += v;
    }
    stat[tid * 5 + 4] = mean * 0.25f;
  }
  __syncthreads();
  float s = b1[tid];
  #pragma unroll
  for (int i = 0; i < 20; ++i) s += stat[i] * w1[i * 64 + tid];
  float hv = s / (1.f + __expf(-s));
  float v = hv * w2[tid];
  #pragma unroll
  for (int o = 32; o; o >>= 1) v += __shfl_down(v, o);
  if (tid == 0) lqe_s = v + b2[0];
  __syncthreads();
  if (tid < 4) out[(size_t)row * 84 + tid] = inter[row * 4 + tid];
  for (int c = tid; c < NC_; c += 64)
    out[(size_t)row * 84 + 4 + c] = scores[(size_t)row * NC_ + c] + lqe_s;
}

// ---------------------------------------------------------------------------
// small elementwise kernels
// ---------------------------------------------------------------------------
__global__ void fill0_kernel(float* __restrict__ p, int n) {
  int i = blockIdx.x * 256 + threadIdx.x; if (i < n) p[i] = 0.f;
}
__global__ void sigmoid_kernel(float* __restrict__ d, const float* __restrict__ s, int n) {
  int i = blockIdx.x * 256 + threadIdx.x; if (i < n) d[i] = 1.f / (1.f + __expf(-s[i]));
}
__global__ void prebb_kernel(float* __restrict__ d, const float* __restrict__ pre,
                             const float* __restrict__ refp, int n) {
  int i = blockIdx.x * 256 + threadIdx.x;
  if (i < n) {
    float x = refp[i];
    x = fminf(fmaxf(x, 1e-5f), 1.f - 1e-5f);
    float is = logf(x) - log1pf(-x);
    d[i] = 1.f / (1.f + __expf(-(pre[i] + is)));
  }
}

// ---------------------------------------------------------------------------
// host orchestration
// ---------------------------------------------------------------------------
static void launch_mfma(hipStream_t st, const float* A, const float* Aadd,
                        const float* Acat, int KA, const short* Wt, const float* bias,
                        const float* Cadd, float* C, int M, int N, int K, int act) {
  dim3 g((N + 63) / 64, M / 64), blk(256);
  switch (act) {
    case 0: mfma_gemm<0><<<g, blk, 0, st>>>(A, Aadd, Acat, KA, Wt, bias, Cadd, C, M, N, K); break;
    case 1: mfma_gemm<1><<<g, blk, 0, st>>>(A, Aadd, Acat, KA, Wt, bias, Cadd, C, M, N, K); break;
    case 2: mfma_gemm<2><<<g, blk, 0, st>>>(A, Aadd, Acat, KA, Wt, bias, Cadd, C, M, N, K); break;
    case 3: mfma_gemm<3><<<g, blk, 0, st>>>(A, Aadd, Acat, KA, Wt, bias, Cadd, C, M, N, K); break;
    case 4: mfma_gemm<4><<<g, blk, 0, st>>>(A, Aadd, Acat, KA, Wt, bias, Cadd, C, M, N, K); break;
  }
}

static void launch_gemm(hipStream_t st, const float* A, const float* W, const float* bias,
                        const float* add, float* C, int M, int N, int K, int act) {
  dim3 g((N + 63) / 64, (M + 63) / 64), blk(256);
  switch (act) {
    case 0: gemm_kernel<0><<<g, blk, 0, st>>>(A, W, bias, add, C, M, N, K); break;
    case 2: gemm_kernel<2><<<g, blk, 0, st>>>(A, W, bias, add, C, M, N, K); break;
  }
}

static void conv_w(hipStream_t st, const float* W, short* Wt, int K, int N, int L) {
  dim3 g((K + 31) / 32, (N + 31) / 32, L);
  wconv_kernel<<<g, 256, 0, st>>>(W, Wt, K, N);
}

static inline dim3 egrid(int n) { return dim3((n + 255) / 256); }

extern "C" void kernel_launch(void* const* d_in, const int* in_sizes, int n_in,
                              void* d_out, int out_size, void* d_ws, size_t ws_size,
                              hipStream_t stream) {
  const float* target     = (const float*)d_in[0];
  const float* ref_unact  = (const float*)d_in[1];
  const float* memory     = (const float*)d_in[2];
  const float* sa_qw = (const float*)d_in[3];  const float* sa_qb = (const float*)d_in[4];
  const float* sa_kw = (const float*)d_in[5];  const float* sa_kb = (const float*)d_in[6];
  const float* sa_vw = (const float*)d_in[7];  const float* sa_vb = (const float*)d_in[8];
  const float* sa_ow = (const float*)d_in[9];  const float* sa_ob = (const float*)d_in[10];
  const float* n1_g  = (const float*)d_in[11]; const float* n1_b  = (const float*)d_in[12];
  const float* off_w = (const float*)d_in[13]; const float* off_b = (const float*)d_in[14];
  const float* aw_w  = (const float*)d_in[15]; const float* aw_b  = (const float*)d_in[16];
  const float* gate_w= (const float*)d_in[17]; const float* gate_b= (const float*)d_in[18];
  const float* gn_g  = (const float*)d_in[19]; const float* gn_b  = (const float*)d_in[20];
  const float* ff1_w = (const float*)d_in[21]; const float* ff1_b = (const float*)d_in[22];
  const float* ff2_w = (const float*)d_in[23]; const float* ff2_b = (const float*)d_in[24];
  const float* n3_g  = (const float*)d_in[25]; const float* n3_b  = (const float*)d_in[26];
  const float* bb_w1 = (const float*)d_in[27]; const float* bb_b1 = (const float*)d_in[28];
  const float* bb_w2 = (const float*)d_in[29]; const float* bb_b2 = (const float*)d_in[30];
  const float* bb_w3 = (const float*)d_in[31]; const float* bb_b3 = (const float*)d_in[32];
  const float* sc_w  = (const float*)d_in[33]; const float* sc_b  = (const float*)d_in[34];
  const float* lqe_w1= (const float*)d_in[35]; const float* lqe_b1= (const float*)d_in[36];
  const float* lqe_w2= (const float*)d_in[37]; const float* lqe_b2= (const float*)d_in[38];
  const float* qp_w1 = (const float*)d_in[39]; const float* qp_b1 = (const float*)d_in[40];
  const float* qp_w2 = (const float*)d_in[41]; const float* qp_b2 = (const float*)d_in[42];
  const float* pb_w1 = (const float*)d_in[43]; const float* pb_b1 = (const float*)d_in[44];
  const float* pb_w2 = (const float*)d_in[45]; const float* pb_b2 = (const float*)d_in[46];
  const float* pb_w3 = (const float*)d_in[47]; const float* pb_b3 = (const float*)d_in[48];
  float* out = (float*)d_out;

  // ---- workspace: fp32 region ----
  float* ws = (float*)d_ws;
  size_t woff = 0;
  auto alloc = [&](size_t n) { float* p = ws + woff; woff += n; return p; };
  float* output   = alloc((size_t)R_ * D_);
  float* out_prev = alloc((size_t)R_ * D_);
  float* qp       = alloc((size_t)R_ * D_);
  float* qbuf     = alloc((size_t)R_ * D_);   // also: offs, pre_bb out, scores
  float* kbuf     = alloc((size_t)R_ * D_);   // also: aw logits; h2
  float* vbuf     = alloc((size_t)R_ * D_);   // also: h1
  float* t2       = alloc((size_t)R_ * D_);
  float* big      = alloc((size_t)R_ * FF_);  // qp hidden (R*512) / g12 / ffn hidden
  float* corners0 = alloc((size_t)R_ * 4 * NBIN_);
  float* corners1 = alloc((size_t)R_ * 4 * NBIN_);
  float* refA     = alloc((size_t)R_ * 4);
  float* refB     = alloc((size_t)R_ * 4);
  float* ref_init = alloc((size_t)R_ * 4);
  float* h1 = vbuf;
  float* h2 = kbuf;
  float* g12 = big + (size_t)R_ * 512;

  // ---- workspace: bf16 (short) region ----
  short* sws = (short*)(ws + woff);
  size_t soff = 0;
  auto salloc = [&](size_t n) { short* p = sws + soff; soff += n; return p; };
  short* qp2t  = salloc(512 * 256);
  short* sqt   = salloc((size_t)NLAYERS_ * 256 * 256);
  short* skt   = salloc((size_t)NLAYERS_ * 256 * 256);
  short* svt   = salloc((size_t)NLAYERS_ * 256 * 256);
  short* sot   = salloc((size_t)NLAYERS_ * 256 * 256);
  short* offt  = salloc((size_t)NLAYERS_ * 192 * 256);
  short* awt   = salloc((size_t)NLAYERS_ * 96 * 256);
  short* gatet = salloc((size_t)NLAYERS_ * 512 * 512);
  short* ff1t  = salloc((size_t)NLAYERS_ * 1024 * 256);
  short* ff2t  = salloc((size_t)NLAYERS_ * 256 * 1024);
  short* bb1t  = salloc((size_t)NLAYERS_ * 256 * 256);
  short* bb2t  = salloc((size_t)NLAYERS_ * 256 * 256);
  short* bb3t  = salloc((size_t)NLAYERS_ * 132 * 256);
  short* pb1t  = salloc(256 * 256);
  short* pb2t  = salloc(256 * 256);
  short* sct   = salloc(80 * 256);
  if (ws_size < woff * sizeof(float) + soff * sizeof(short)) return;

  float* c_prev = corners0; float* c_cur = corners1;
  float* ref_cur = refA;    float* ref_nxt = refB;

  // ---- weight convert+transpose (bf16) ----
  conv_w(stream, qp_w2, qp2t, 512, 256, 1);
  conv_w(stream, sa_qw, sqt, 256, 256, NLAYERS_);
  conv_w(stream, sa_kw, skt, 256, 256, NLAYERS_);
  conv_w(stream, sa_vw, svt, 256, 256, NLAYERS_);
  conv_w(stream, sa_ow, sot, 256, 256, NLAYERS_);
  conv_w(stream, off_w, offt, 256, 192, NLAYERS_);
  conv_w(stream, aw_w, awt, 256, 96, NLAYERS_);
  conv_w(stream, gate_w, gatet, 512, 512, NLAYERS_);
  conv_w(stream, ff1_w, ff1t, 256, 1024, NLAYERS_);
  conv_w(stream, ff2_w, ff2t, 1024, 256, NLAYERS_);
  conv_w(stream, bb_w1, bb1t, 256, 256, NLAYERS_);
  conv_w(stream, bb_w2, bb2t, 256, 256, NLAYERS_);
  conv_w(stream, bb_w3, bb3t, 256, 132, NLAYERS_);
  conv_w(stream, pb_w1, pb1t, 256, 256, 1);
  conv_w(stream, pb_w2, pb2t, 256, 256, 1);
  conv_w(stream, sc_w + (size_t)5 * D_ * NC_, sct, 256, 80, 1);

  // ---- init ----
  fill0_kernel<<<egrid(R_ * D_), 256, 0, stream>>>(out_prev, R_ * D_);
  fill0_kernel<<<egrid(R_ * 4 * NBIN_), 256, 0, stream>>>(c_prev, R_ * 4 * NBIN_);
  sigmoid_kernel<<<egrid(R_ * 4), 256, 0, stream>>>(ref_cur, ref_unact, R_ * 4);
  hipMemcpyAsync(output, target, (size_t)R_ * D_ * sizeof(float),
                 hipMemcpyDeviceToDevice, stream);

  for (int i = 0; i < NLAYERS_; ++i) {
    // qp = clip(mlp2(ref_pts), -10, 10)
    launch_gemm(stream, ref_cur, qp_w1, qp_b1, nullptr, big, R_, 512, 4, 2);
    launch_mfma(stream, big, nullptr, nullptr, 0, qp2t, qp_b2, nullptr, qp, R_, D_, 512, 4);

    // ---- self attention ----
    launch_mfma(stream, output, qp, nullptr, 0, sqt + (size_t)i*65536, sa_qb + (size_t)i*D_,
                nullptr, qbuf, R_, D_, D_, 0);
    launch_mfma(stream, output, qp, nullptr, 0, skt + (size_t)i*65536, sa_kb + (size_t)i*D_,
                nullptr, kbuf, R_, D_, D_, 0);
    launch_mfma(stream, output, nullptr, nullptr, 0, svt + (size_t)i*65536, sa_vb + (size_t)i*D_,
                nullptr, vbuf, R_, D_, D_, 0);
    attn2_kernel<<<dim3(B_ * NH_ * 2), 192, 0, stream>>>(qbuf, kbuf, vbuf, t2);
    launch_mfma(stream, t2, nullptr, nullptr, 0, sot + (size_t)i*65536, sa_ob + (size_t)i*D_,
                nullptr, h1, R_, D_, D_, 0);
    ln_kernel<0><<<dim3(R_), 256, 0, stream>>>(output, output, h1, nullptr,
                                               n1_g + (size_t)i*D_, n1_b + (size_t)i*D_);

    // ---- deformable cross attention ----
    launch_mfma(stream, output, qp, nullptr, 0, offt + (size_t)i*49152,
                off_b + (size_t)i*TOT_*2, nullptr, qbuf, R_, TOT_*2, D_, 0);
    launch_mfma(stream, output, qp, nullptr, 0, awt + (size_t)i*24576,
                aw_b + (size_t)i*TOT_, nullptr, kbuf, R_, TOT_, D_, 0);
    deform_kernel<<<dim3(R_), 256, 0, stream>>>(memory, qbuf, kbuf, ref_cur, t2);

    // ---- gateway (concat folded into A-staging) ----
    launch_mfma(stream, output, nullptr, t2, 256, gatet + (size_t)i*262144,
                gate_b + (size_t)i*512, nullptr, g12, R_, 512, 512, 3);
    ln_kernel<2><<<dim3(R_), 256, 0, stream>>>(output, output, t2, g12,
                                               gn_g + (size_t)i*D_, gn_b + (size_t)i*D_);

    // ---- FFN ----
    launch_mfma(stream, output, nullptr, nullptr, 0, ff1t + (size_t)i*262144,
                ff1_b + (size_t)i*FF_, nullptr, big, R_, FF_, D_, 1);
    launch_mfma(stream, big, nullptr, nullptr, 0, ff2t + (size_t)i*262144,
                ff2_b + (size_t)i*D_, nullptr, t2, R_, D_, FF_, 0);
    ln_kernel<1><<<dim3(R_), 256, 0, stream>>>(output, output, t2, nullptr,
                                               n3_g + (size_t)i*D_, n3_b + (size_t)i*D_);

    // ---- FDR box refinement ----
    if (i == 0) {
      launch_mfma(stream, output, nullptr, nullptr, 0, pb1t, pb_b1, nullptr, h1, R_, D_, D_, 2);
      launch_mfma(stream, h1, nullptr, nullptr, 0, pb2t, pb_b2, nullptr, h2, R_, D_, D_, 2);
      launch_gemm(stream, h2, pb_w3, pb_b3, nullptr, qbuf, R_, 4, D_, 0);
      prebb_kernel<<<egrid(R_ * 4), 256, 0, stream>>>(ref_init, qbuf, ref_cur, R_ * 4);
    }
    launch_mfma(stream, output, out_prev, nullptr, 0, bb1t + (size_t)i*65536,
                bb_b1 + (size_t)i*D_, nullptr, h1, R_, D_, D_, 2);
    launch_mfma(stream, h1, nullptr, nullptr, 0, bb2t + (size_t)i*65536,
                bb_b2 + (size_t)i*D_, nullptr, h2, R_, D_, D_, 2);
    launch_mfma(stream, h2, nullptr, nullptr, 0, bb3t + (size_t)i*33792,
                bb_b3 + (size_t)i*4*NBIN_, c_prev, c_cur, R_, 4*NBIN_, D_, 0);
    bbox_kernel<<<egrid(R_), 256, 0, stream>>>(c_cur, ref_init, ref_nxt);

    if (i == NLAYERS_ - 1) {
      launch_mfma(stream, output, nullptr, nullptr, 0, sct, sc_b + (size_t)5*NC_,
                  nullptr, qbuf, R_, NC_, D_, 0);
      lqe_kernel<<<dim3(R_), 64, 0, stream>>>(qbuf, c_cur,
                                              lqe_w1 + (size_t)5*20*64, lqe_b1 + (size_t)5*64,
                                              lqe_w2 + (size_t)5*64, lqe_b2 + (size_t)5,
                                              ref_nxt, out);
    } else {
      hipMemcpyAsync(out_prev, output, (size_t)R_ * D_ * sizeof(float),
                     hipMemcpyDeviceToDevice, stream);
      std::swap(c_prev, c_cur);
      std::swap(ref_cur, ref_nxt);
    }
  }
}

// Round 3
// 2279.160 us; speedup vs baseline: 3.7594x; 1.2531x over previous
//
#include <hip/hip_runtime.h>
#include <cstddef>
#include <cmath>
#include <utility>

#define B_ 16
#define LQ_ 300
#define D_ 256
#define NH_ 8
#define HD_ 32
#define FF_ 1024
#define NBIN_ 33
#define NC_ 80
#define SUMP_ 12
#define TOT_ (NH_*SUMP_)   // 96
#define STOT_ 8400
#define R_ (B_*LQ_)        // 4800
#define NLAYERS_ 6

typedef short bf16x8 __attribute__((ext_vector_type(8)));
typedef float f32x4  __attribute__((ext_vector_type(4)));

static __device__ __forceinline__ short f2bf(float x) {
  union { float f; unsigned u; } v; v.f = x;
  unsigned r = v.u + 0x7fffu + ((v.u >> 16) & 1u);   // RNE
  return (short)(r >> 16);
}

// ---------------------------------------------------------------------------
// Weight convert+transpose: W [K,N] fp32 -> Wt [N,K] bf16 at out-stride.
// ---------------------------------------------------------------------------
__launch_bounds__(256)
__global__ void wconv_kernel(const float* __restrict__ W, short* __restrict__ Wt,
                             int K, int N, size_t ostride) {
  __shared__ float t[32][33];
  const float* Wl = W + (size_t)blockIdx.z * K * N;
  short* Wtl = Wt + (size_t)blockIdx.z * ostride;
  int k0 = blockIdx.x * 32, n0 = blockIdx.y * 32;
  int tr = threadIdx.x >> 5, tc = threadIdx.x & 31;
  #pragma unroll
  for (int i = 0; i < 4; ++i) {
    int k = k0 + tr + i * 8, n = n0 + tc;
    t[tr + i * 8][tc] = (k < K && n < N) ? Wl[(size_t)k * N + n] : 0.f;
  }
  __syncthreads();
  #pragma unroll
  for (int i = 0; i < 4; ++i) {
    int n = n0 + tr + i * 8, k = k0 + tc;
    if (n < N && k < K) Wtl[(size_t)n * K + k] = f2bf(t[tc][tr + i * 8]);
  }
}

// ---------------------------------------------------------------------------
// Barrier-free bf16 MFMA GEMM. C = act(Asel @ Wt^T + bias [+Cadd]).
//  - A selection: n-based (A2 for bn>=N2) or k-based concat (Acat for k>=KA).
//  - A, A2, Acat, Wt are bf16; fragments loaded straight from global (no LDS,
//    no __syncthreads). Block 256thr = 4 waves, tile 64x64, wave 32x32.
//  - Outputs: Cf (fp32) and/or Cbf (bf16), both optional.
// Requires M % 64 == 0, K % 32 == 0, KA % 32 == 0.
// ACT: 0 none, 1 relu, 2 silu, 3 sigmoid, 4 clip(+-10)
// ---------------------------------------------------------------------------
template<int ACT>
__launch_bounds__(256)
__global__ void bgemm(const short* __restrict__ A, const short* __restrict__ A2, int N2,
                      const short* __restrict__ Acat, int KA,
                      const short* __restrict__ Wt, const float* __restrict__ bias,
                      const float* __restrict__ Cadd, float* __restrict__ Cf,
                      short* __restrict__ Cbf, int M, int N, int K) {
  const int bm = blockIdx.y * 64, bn = blockIdx.x * 64;
  const int tid = threadIdx.x, wid = tid >> 6, lane = tid & 63;
  const int wm = (wid >> 1) * 32, wn = (wid & 1) * 32;
  const int lr = lane & 15, lq = lane >> 4;
  const short* Ab = (A2 && bn >= N2) ? A2 : A;
  const int lda = Acat ? KA : K;
  const int ldb = K - KA;
  const int r0 = bm + wm + lr, r1 = r0 + 16;
  const int n0 = bn + wn + lr, n1 = n0 + 16;
  const bool v0 = n0 < N, v1 = n1 < N;
  f32x4 acc[2][2];
  #pragma unroll
  for (int i = 0; i < 2; ++i)
    #pragma unroll
    for (int j = 0; j < 2; ++j) acc[i][j] = (f32x4){0.f, 0.f, 0.f, 0.f};

  for (int k0 = 0; k0 < K; k0 += 32) {
    const short* src; int ko, ld;
    if (Acat && k0 >= KA) { src = Acat; ko = k0 - KA; ld = ldb; }
    else                  { src = Ab;   ko = k0;      ld = lda; }
    bf16x8 a0 = *(const bf16x8*)(src + (size_t)r0 * ld + ko + lq * 8);
    bf16x8 a1 = *(const bf16x8*)(src + (size_t)r1 * ld + ko + lq * 8);
    bf16x8 w0 = v0 ? *(const bf16x8*)(Wt + (size_t)n0 * K + k0 + lq * 8)
                   : (bf16x8){0,0,0,0,0,0,0,0};
    bf16x8 w1 = v1 ? *(const bf16x8*)(Wt + (size_t)n1 * K + k0 + lq * 8)
                   : (bf16x8){0,0,0,0,0,0,0,0};
    acc[0][0] = __builtin_amdgcn_mfma_f32_16x16x32_bf16(a0, w0, acc[0][0], 0, 0, 0);
    acc[0][1] = __builtin_amdgcn_mfma_f32_16x16x32_bf16(a0, w1, acc[0][1], 0, 0, 0);
    acc[1][0] = __builtin_amdgcn_mfma_f32_16x16x32_bf16(a1, w0, acc[1][0], 0, 0, 0);
    acc[1][1] = __builtin_amdgcn_mfma_f32_16x16x32_bf16(a1, w1, acc[1][1], 0, 0, 0);
  }
  #pragma unroll
  for (int ti = 0; ti < 2; ++ti)
    #pragma unroll
    for (int tj = 0; tj < 2; ++tj) {
      int gn = bn + wn + tj * 16 + lr;
      if (gn >= N) continue;
      float bv = bias[gn];
      #pragma unroll
      for (int r = 0; r < 4; ++r) {
        int gm = bm + wm + ti * 16 + lq * 4 + r;
        float v = acc[ti][tj][r] + bv;
        if (Cadd) v += Cadd[(size_t)gm * N + gn];
        if (ACT == 1) v = fmaxf(v, 0.f);
        if (ACT == 2) v = v / (1.f + __expf(-v));
        if (ACT == 3) v = 1.f / (1.f + __expf(-v));
        if (ACT == 4) v = fminf(fmaxf(v, -10.f), 10.f);
        if (Cf)  Cf[(size_t)gm * N + gn] = v;
        if (Cbf) Cbf[(size_t)gm * N + gn] = f2bf(v);
      }
    }
}

// ---------------------------------------------------------------------------
// fp32 GEMM for qp layer1 only (K=4). Writes bf16 output.
// ---------------------------------------------------------------------------
__launch_bounds__(256)
__global__ void gemm_qp1(const float* __restrict__ A, const float* __restrict__ W,
                         const float* __restrict__ bias, short* __restrict__ Cbf,
                         int M, int N, int K) {
  __shared__ float As[16][65];
  __shared__ float Ws[16][65];
  const int bm = blockIdx.y * 64, bn = blockIdx.x * 64;
  const int tid = threadIdx.x;
  const int tm = (tid >> 4) << 2;
  const int tn = (tid & 15) << 2;
  float acc[4][4] = {};
  for (int k0 = 0; k0 < K; k0 += 16) {
    #pragma unroll
    for (int t = 0; t < 4; ++t) {
      int idx = tid + t * 256;
      int mm = idx >> 4, kk = idx & 15;
      int gm = bm + mm, gk = k0 + kk;
      As[kk][mm] = (gm < M && gk < K) ? A[(size_t)gm * K + gk] : 0.f;
      int kk2 = idx >> 6, nn = idx & 63;
      int gk2 = k0 + kk2, gn = bn + nn;
      Ws[kk2][nn] = (gk2 < K && gn < N) ? W[(size_t)gk2 * N + gn] : 0.f;
    }
    __syncthreads();
    #pragma unroll
    for (int kk = 0; kk < 16; ++kk) {
      float a0 = As[kk][tm], a1 = As[kk][tm+1], a2 = As[kk][tm+2], a3 = As[kk][tm+3];
      float w0 = Ws[kk][tn], w1 = Ws[kk][tn+1], w2 = Ws[kk][tn+2], w3 = Ws[kk][tn+3];
      acc[0][0] += a0*w0; acc[0][1] += a0*w1; acc[0][2] += a0*w2; acc[0][3] += a0*w3;
      acc[1][0] += a1*w0; acc[1][1] += a1*w1; acc[1][2] += a1*w2; acc[1][3] += a1*w3;
      acc[2][0] += a2*w0; acc[2][1] += a2*w1; acc[2][2] += a2*w2; acc[2][3] += a2*w3;
      acc[3][0] += a3*w0; acc[3][1] += a3*w1; acc[3][2] += a3*w2; acc[3][3] += a3*w3;
    }
    __syncthreads();
  }
  #pragma unroll
  for (int i = 0; i < 4; ++i) {
    int gm = bm + tm + i; if (gm >= M) continue;
    #pragma unroll
    for (int j = 0; j < 4; ++j) {
      int gn = bn + tn + j; if (gn >= N) continue;
      float v = acc[i][j] + bias[gn];
      v = v / (1.f + __expf(-v));    // silu
      Cbf[(size_t)gm * N + gn] = f2bf(v);
    }
  }
}

// ---------------------------------------------------------------------------
// LayerNorm (fused add/gate) over D=256. Writes fp32 + optional bf16.
// ---------------------------------------------------------------------------
template<int MODE>
__launch_bounds__(256)
__global__ void ln_kernel(float* __restrict__ out, short* __restrict__ outbf,
                          const float* __restrict__ a, const float* __restrict__ b,
                          const float* __restrict__ g12,
                          const float* __restrict__ gamma, const float* __restrict__ beta) {
  const int row = blockIdx.x, c = threadIdx.x;
  const size_t off = (size_t)row * D_ + c;
  float x;
  if (MODE == 0) x = a[off] + b[off];
  else if (MODE == 1) { x = a[off] + b[off]; x = fminf(fmaxf(x, -65504.f), 65504.f); }
  else {
    float g1 = g12[(size_t)row * 2 * D_ + c];
    float g2 = g12[(size_t)row * 2 * D_ + D_ + c];
    x = g1 * a[off] + g2 * b[off];
  }
  __shared__ float red[8];
  float s = x;
  #pragma unroll
  for (int o = 32; o; o >>= 1) s += __shfl_down(s, o);
  if ((c & 63) == 0) red[c >> 6] = s;
  __syncthreads();
  float mu = (red[0] + red[1] + red[2] + red[3]) * (1.f / D_);
  float dd = x - mu;
  float s2 = dd * dd;
  #pragma unroll
  for (int o = 32; o; o >>= 1) s2 += __shfl_down(s2, o);
  if ((c & 63) == 0) red[4 + (c >> 6)] = s2;
  __syncthreads();
  float var = (red[4] + red[5] + red[6] + red[7]) * (1.f / D_);
  float v = dd * rsqrtf(var + 1e-5f) * gamma[c] + beta[c];
  out[off] = v;
  if (outbf) outbf[off] = f2bf(v);
}

// ---------------------------------------------------------------------------
// MFMA self-attention. Block per (b,h,half): 150 queries, 4 waves.
// qkv bf16 [R,768] (q|k|v each 256 cols, head at h*32). O bf16 [R,256].
// ---------------------------------------------------------------------------
__launch_bounds__(256)
__global__ void attn3_kernel(const short* __restrict__ qkv, short* __restrict__ O) {
  __shared__ short Kb[304][40];
  __shared__ short Vt[32][328];
  __shared__ short Pw[4][16][328];
  const int half = blockIdx.x & 1, bh = blockIdx.x >> 1;
  const int h = bh & 7, b = bh >> 3;
  const int tid = threadIdx.x;
  const short* QKVb = qkv + (size_t)b * LQ_ * 768;
  // stage K (rows 300..303 zero)
  for (int idx = tid; idx < 304 * 4; idx += 256) {
    int row = idx >> 2, seg = (idx & 3) * 8;
    bf16x8 v = (row < 300) ? *(const bf16x8*)(QKVb + (size_t)row * 768 + 256 + h * 32 + seg)
                           : (bf16x8){0,0,0,0,0,0,0,0};
    *(bf16x8*)&Kb[row][seg] = v;
  }
  // stage V transposed
  for (int idx = tid; idx < 300 * 4; idx += 256) {
    int row = idx >> 2, seg = (idx & 3) * 8;
    bf16x8 v = *(const bf16x8*)(QKVb + (size_t)row * 768 + 512 + h * 32 + seg);
    #pragma unroll
    for (int j = 0; j < 8; ++j) Vt[seg + j][row] = v[j];
  }
  // zero pads: Vt cols 300..319, Pw cols 304..319
  for (int idx = tid; idx < 32 * 20; idx += 256) Vt[idx / 20][300 + idx % 20] = 0;
  for (int idx = tid; idx < 4 * 16 * 16; idx += 256)
    Pw[idx >> 8][(idx >> 4) & 15][304 + (idx & 15)] = 0;
  __syncthreads();

  const int wid = tid >> 6, lane = tid & 63;
  const int lr = lane & 15, lq = lane >> 4;
  short (*Pl)[328] = Pw[wid];
  const float scale = 0.17677669529663687f;

  for (int qt = wid; qt < 10; qt += 4) {
    const int q0 = half * 150 + qt * 16;
    int qrow = q0 + lr; if (qrow > 299) qrow = 299;
    bf16x8 af_q = *(const bf16x8*)(QKVb + (size_t)qrow * 768 + h * 32 + lq * 8);
    f32x4 s[19];
    #pragma unroll
    for (int t = 0; t < 19; ++t) {
      bf16x8 bk = *(const bf16x8*)&Kb[t * 16 + lr][lq * 8];
      s[t] = __builtin_amdgcn_mfma_f32_16x16x32_bf16(af_q, bk, (f32x4){0.f,0.f,0.f,0.f}, 0, 0, 0);
    }
    #pragma unroll
    for (int t = 0; t < 19; ++t)
      #pragma unroll
      for (int r = 0; r < 4; ++r) s[t][r] *= scale;
    if (lr >= 12) { s[18][0] = s[18][1] = s[18][2] = s[18][3] = -1e30f; }
    float l[4];
    #pragma unroll
    for (int r = 0; r < 4; ++r) {
      float mm = -1e30f;
      #pragma unroll
      for (int t = 0; t < 19; ++t) mm = fmaxf(mm, s[t][r]);
      #pragma unroll
      for (int x = 1; x < 16; x <<= 1) mm = fmaxf(mm, __shfl_xor(mm, x));
      float ll = 0.f;
      #pragma unroll
      for (int t = 0; t < 19; ++t) { float p = __expf(s[t][r] - mm); s[t][r] = p; ll += p; }
      #pragma unroll
      for (int x = 1; x < 16; x <<= 1) ll += __shfl_xor(ll, x);
      l[r] = ll;
    }
    #pragma unroll
    for (int t = 0; t < 19; ++t)
      #pragma unroll
      for (int r = 0; r < 4; ++r) Pl[lq * 4 + r][t * 16 + lr] = f2bf(s[t][r]);
    // wave-private LDS round-trip (no barrier needed)
    f32x4 o0 = (f32x4){0.f,0.f,0.f,0.f}, o1 = (f32x4){0.f,0.f,0.f,0.f};
    #pragma unroll
    for (int c = 0; c < 10; ++c) {
      bf16x8 ap = *(const bf16x8*)&Pl[lr][c * 32 + lq * 8];
      bf16x8 v0 = *(const bf16x8*)&Vt[lr][c * 32 + lq * 8];
      bf16x8 v1 = *(const bf16x8*)&Vt[16 + lr][c * 32 + lq * 8];
      o0 = __builtin_amdgcn_mfma_f32_16x16x32_bf16(ap, v0, o0, 0, 0, 0);
      o1 = __builtin_amdgcn_mfma_f32_16x16x32_bf16(ap, v1, o1, 0, 0, 0);
    }
    #pragma unroll
    for (int r = 0; r < 4; ++r) {
      int q = q0 + lq * 4 + r;
      if (q >= 300) continue;
      float inv = 1.f / l[r];
      size_t ob = (size_t)(b * LQ_ + q) * 256 + h * 32;
      O[ob + lr]      = f2bf(o0[r] * inv);
      O[ob + 16 + lr] = f2bf(o1[r] * inv);
    }
  }
}

// ---------------------------------------------------------------------------
// Deformable sampling. offaw fp32 [R,288] = offs(192)|aw(96).
// Writes t2 fp32 + bf16.
// ---------------------------------------------------------------------------
__launch_bounds__(256)
__global__ void deform_kernel(const float* __restrict__ mem, const float* __restrict__ offaw,
                              const float* __restrict__ refp,
                              float* __restrict__ t2, short* __restrict__ t2bf) {
  const int row = blockIdx.x;
  const int b = row / LQ_;
  const int tid = threadIdx.x;
  const int h = tid >> 5, c = tid & 31;
  const float rx = refp[row * 4 + 0], ry = refp[row * 4 + 1];
  const float rw = refp[row * 4 + 2], rh = refp[row * 4 + 3];
  const float* awp = offaw + (size_t)row * 288 + 192 + h * SUMP_;
  float wv[SUMP_];
  float wmax = -1e30f;
  #pragma unroll
  for (int p = 0; p < SUMP_; ++p) { wv[p] = awp[p]; wmax = fmaxf(wmax, wv[p]); }
  float wsum = 0.f;
  #pragma unroll
  for (int p = 0; p < SUMP_; ++p) { wv[p] = __expf(wv[p] - wmax); wsum += wv[p]; }
  const float winv = 1.f / wsum;
  const float* op = offaw + (size_t)row * 288 + h * (SUMP_ * 2);
  const float* mbase = mem + (size_t)b * STOT_ * D_ + h * HD_ + c;
  float acc = 0.f;
  #pragma unroll
  for (int p = 0; p < SUMP_; ++p) {
    const int lvl = p >> 2;
    const int Wl = (lvl == 0) ? 80 : ((lvl == 1) ? 40 : 20);
    const int Hl = Wl;
    const int s0 = (lvl == 0) ? 0 : ((lvl == 1) ? 6400 : 8000);
    float lx = rx + op[2 * p]     * 0.125f * rw;
    float ly = ry + op[2 * p + 1] * 0.125f * rh;
    float x = lx * Wl - 0.5f, y = ly * Hl - 0.5f;
    float xf = floorf(x), yf = floorf(y);
    int x0 = (int)xf, y0 = (int)yf;
    float wx = x - xf, wy = y - yf;
    const float* mb = mbase + (size_t)s0 * D_;
    float v = 0.f;
    bool xv0 = (x0 >= 0) && (x0 < Wl), xv1 = (x0 + 1 >= 0) && (x0 + 1 < Wl);
    bool yv0 = (y0 >= 0) && (y0 < Hl), yv1 = (y0 + 1 >= 0) && (y0 + 1 < Hl);
    if (yv0) {
      if (xv0) v += (1.f - wx) * (1.f - wy) * mb[(size_t)(y0 * Wl + x0) * D_];
      if (xv1) v += wx * (1.f - wy) * mb[(size_t)(y0 * Wl + x0 + 1) * D_];
    }
    if (yv1) {
      if (xv0) v += (1.f - wx) * wy * mb[(size_t)((y0 + 1) * Wl + x0) * D_];
      if (xv1) v += wx * wy * mb[(size_t)((y0 + 1) * Wl + x0 + 1) * D_];
    }
    acc += wv[p] * winv * v;
  }
  acc = acc;
  size_t off = (size_t)row * D_ + h * HD_ + c;
  t2[off] = acc;
  t2bf[off] = f2bf(acc);
}

// ---------------------------------------------------------------------------
// corners -> dist -> distance2bbox
// ---------------------------------------------------------------------------
__launch_bounds__(256)
__global__ void bbox_kernel(const float* __restrict__ corners, const float* __restrict__ refi,
                            float* __restrict__ inter) {
  int row = blockIdx.x * blockDim.x + threadIdx.x;
  if (row >= R_) return;
  float proj[NBIN_];
  proj[0] = -4.f; proj[16] = 0.f; proj[32] = 4.f;
  const float step = powf(3.f, 1.f / 15.f);
  float pw = 1.f;
  for (int i = 1; i <= 15; ++i) { pw *= step; proj[16 + i] = pw - 1.f; proj[16 - i] = 1.f - pw; }
  float dist[4];
  for (int s = 0; s < 4; ++s) {
    const float* cp = corners + (size_t)row * (4 * NBIN_) + s * NBIN_;
    float m = -1e30f;
    for (int j = 0; j < NBIN_; ++j) m = fmaxf(m, cp[j]);
    float sum = 0.f, dot = 0.f;
    for (int j = 0; j < NBIN_; ++j) { float e = __expf(cp[j] - m); sum += e; dot += e * proj[j]; }
    dist[s] = dot / sum;
  }
  float px = refi[row * 4], py = refi[row * 4 + 1];
  float qw = refi[row * 4 + 2] * 0.25f, qh = refi[row * 4 + 3] * 0.25f;
  float x1 = px - (2.f + dist[0]) * qw, y1 = py - (2.f + dist[1]) * qh;
  float x2 = px + (2.f + dist[2]) * qw, y2 = py + (2.f + dist[3]) * qh;
  inter[row * 4 + 0] = (x1 + x2) * 0.5f;
  inter[row * 4 + 1] = (y1 + y2) * 0.5f;
  inter[row * 4 + 2] = x2 - x1;
  inter[row * 4 + 3] = y2 - y1;
}

// ---------------------------------------------------------------------------
// LQE head + final output assembly.
// ---------------------------------------------------------------------------
__launch_bounds__(64)
__global__ void lqe_kernel(const float* __restrict__ scores, const float* __restrict__ corners,
                           const float* __restrict__ w1, const float* __restrict__ b1,
                           const float* __restrict__ w2, const float* __restrict__ b2,
                           const float* __restrict__ inter, float* __restrict__ out) {
  const int row = blockIdx.x;
  const int tid = threadIdx.x;
  __shared__ float stat[20];
  __shared__ float lqe_s;
  if (tid < 4) {
    const float* cp = corners + (size_t)row * (4 * NBIN_) + tid * NBIN_;
    float m = -1e30f;
    for (int j = 0; j < NBIN_; ++j) m = fmaxf(m, cp[j]);
    float e[NBIN_]; float sum = 0.f;
    for (int j = 0; j < NBIN_; ++j) { e[j] = __expf(cp[j] - m); sum += e[j]; }
    float inv = 1.f / sum;
    float mean = 0.f;
    for (int t = 0; t < 4; ++t) {
      int bi = 0; float best = -1.f;
      for (int j = 0; j < NBIN_; ++j) if (e[j] > best) { best = e[j]; bi = j; }
      e[bi] = -2.f;
      float v = best * inv;
      stat[tid * 5 + t] = v; mean += v;
    }
    stat[tid * 5 + 4] = mean * 0.25f;
  }
  __syncthreads();
  float s = b1[tid];
  #pragma unroll
  for (int i = 0; i < 20; ++i) s += stat[i] * w1[i * 64 + tid];
  float hv = s / (1.f + __expf(-s));
  float v = hv * w2[tid];
  #pragma unroll
  for (int o = 32; o; o >>= 1) v += __shfl_down(v, o);
  if (tid == 0) lqe_s = v + b2[0];
  __syncthreads();
  if (tid < 4) out[(size_t)row * 84 + tid] = inter[row * 4 + tid];
  for (int c = tid; c < NC_; c += 64)
    out[(size_t)row * 84 + 4 + c] = scores[(size_t)row * NC_ + c] + lqe_s;
}

// ---------------------------------------------------------------------------
// small elementwise kernels
// ---------------------------------------------------------------------------
__global__ void fill0_kernel(float* __restrict__ p, int n) {
  int i = blockIdx.x * 256 + threadIdx.x; if (i < n) p[i] = 0.f;
}
__global__ void sigmoid_kernel(float* __restrict__ d, const float* __restrict__ s, int n) {
  int i = blockIdx.x * 256 + threadIdx.x; if (i < n) d[i] = 1.f / (1.f + __expf(-s[i]));
}
__global__ void prebb_kernel(float* __restrict__ d, const float* __restrict__ pre,
                             const float* __restrict__ refp, int n) {
  int i = blockIdx.x * 256 + threadIdx.x;
  if (i < n) {
    float x = refp[i];
    x = fminf(fmaxf(x, 1e-5f), 1.f - 1e-5f);
    float is = logf(x) - log1pf(-x);
    d[i] = 1.f / (1.f + __expf(-(pre[i] + is)));
  }
}
// d = bf16(a + b), vectorized x4
__global__ void addbf_kernel(short* __restrict__ d, const float* __restrict__ a,
                             const float* __restrict__ b, int n4) {
  int i = blockIdx.x * 256 + threadIdx.x;
  if (i < n4) {
    float4 va = ((const float4*)a)[i], vb = ((const float4*)b)[i];
    short4 s; s.x = f2bf(va.x + vb.x); s.y = f2bf(va.y + vb.y);
    s.z = f2bf(va.z + vb.z); s.w = f2bf(va.w + vb.w);
    ((short4*)d)[i] = s;
  }
}
__global__ void cvtbf_kernel(short* __restrict__ d, const float* __restrict__ a, int n4) {
  int i = blockIdx.x * 256 + threadIdx.x;
  if (i < n4) {
    float4 va = ((const float4*)a)[i];
    short4 s; s.x = f2bf(va.x); s.y = f2bf(va.y); s.z = f2bf(va.z); s.w = f2bf(va.w);
    ((short4*)d)[i] = s;
  }
}
// concat biases: qkvb [L,768] from qb|kb|vb; offawb [L,288] from ob|ab
__global__ void bcat_kernel(const float* __restrict__ qb, const float* __restrict__ kb,
                            const float* __restrict__ vb, const float* __restrict__ ob,
                            const float* __restrict__ ab, float* __restrict__ qkvb,
                            float* __restrict__ offawb) {
  int i = blockIdx.x * 256 + threadIdx.x;
  if (i < NLAYERS_ * 768) {
    int l = i / 768, c = i % 768;
    qkvb[i] = (c < 256) ? qb[l * 256 + c] : (c < 512) ? kb[l * 256 + c - 256]
                        : vb[l * 256 + c - 512];
  }
  if (i < NLAYERS_ * 288) {
    int l = i / 288, c = i % 288;
    offawb[i] = (c < 192) ? ob[l * 192 + c] : ab[l * 96 + c - 192];
  }
}

// ---------------------------------------------------------------------------
// host orchestration
// ---------------------------------------------------------------------------
static void launch_bgemm(hipStream_t st, const short* A, const short* A2, int N2,
                         const short* Acat, int KA, const short* Wt, const float* bias,
                         const float* Cadd, float* Cf, short* Cbf,
                         int M, int N, int K, int act) {
  dim3 g((N + 63) / 64, M / 64), blk(256);
  switch (act) {
    case 0: bgemm<0><<<g, blk, 0, st>>>(A, A2, N2, Acat, KA, Wt, bias, Cadd, Cf, Cbf, M, N, K); break;
    case 1: bgemm<1><<<g, blk, 0, st>>>(A, A2, N2, Acat, KA, Wt, bias, Cadd, Cf, Cbf, M, N, K); break;
    case 2: bgemm<2><<<g, blk, 0, st>>>(A, A2, N2, Acat, KA, Wt, bias, Cadd, Cf, Cbf, M, N, K); break;
    case 3: bgemm<3><<<g, blk, 0, st>>>(A, A2, N2, Acat, KA, Wt, bias, Cadd, Cf, Cbf, M, N, K); break;
    case 4: bgemm<4><<<g, blk, 0, st>>>(A, A2, N2, Acat, KA, Wt, bias, Cadd, Cf, Cbf, M, N, K); break;
  }
}

static void conv_w(hipStream_t st, const float* W, short* Wt, int K, int N, int L,
                   size_t ostride) {
  dim3 g((K + 31) / 32, (N + 31) / 32, L);
  wconv_kernel<<<g, 256, 0, st>>>(W, Wt, K, N, ostride);
}

static inline dim3 egrid(int n) { return dim3((n + 255) / 256); }

extern "C" void kernel_launch(void* const* d_in, const int* in_sizes, int n_in,
                              void* d_out, int out_size, void* d_ws, size_t ws_size,
                              hipStream_t stream) {
  const float* target     = (const float*)d_in[0];
  const float* ref_unact  = (const float*)d_in[1];
  const float* memory     = (const float*)d_in[2];
  const float* sa_qw = (const float*)d_in[3];  const float* sa_qb = (const float*)d_in[4];
  const float* sa_kw = (const float*)d_in[5];  const float* sa_kb = (const float*)d_in[6];
  const float* sa_vw = (const float*)d_in[7];  const float* sa_vb = (const float*)d_in[8];
  const float* sa_ow = (const float*)d_in[9];  const float* sa_ob = (const float*)d_in[10];
  const float* n1_g  = (const float*)d_in[11]; const float* n1_b  = (const float*)d_in[12];
  const float* off_w = (const float*)d_in[13]; const float* off_b = (const float*)d_in[14];
  const float* aw_w  = (const float*)d_in[15]; const float* aw_b  = (const float*)d_in[16];
  const float* gate_w= (const float*)d_in[17]; const float* gate_b= (const float*)d_in[18];
  const float* gn_g  = (const float*)d_in[19]; const float* gn_b  = (const float*)d_in[20];
  const float* ff1_w = (const float*)d_in[21]; const float* ff1_b = (const float*)d_in[22];
  const float* ff2_w = (const float*)d_in[23]; const float* ff2_b = (const float*)d_in[24];
  const float* n3_g  = (const float*)d_in[25]; const float* n3_b  = (const float*)d_in[26];
  const float* bb_w1 = (const float*)d_in[27]; const float* bb_b1 = (const float*)d_in[28];
  const float* bb_w2 = (const float*)d_in[29]; const float* bb_b2 = (const float*)d_in[30];
  const float* bb_w3 = (const float*)d_in[31]; const float* bb_b3 = (const float*)d_in[32];
  const float* sc_w  = (const float*)d_in[33]; const float* sc_b  = (const float*)d_in[34];
  const float* lqe_w1= (const float*)d_in[35]; const float* lqe_b1= (const float*)d_in[36];
  const float* lqe_w2= (const float*)d_in[37]; const float* lqe_b2= (const float*)d_in[38];
  const float* qp_w1 = (const float*)d_in[39]; const float* qp_b1 = (const float*)d_in[40];
  const float* qp_w2 = (const float*)d_in[41]; const float* qp_b2 = (const float*)d_in[42];
  const float* pb_w1 = (const float*)d_in[43]; const float* pb_b1 = (const float*)d_in[44];
  const float* pb_w2 = (const float*)d_in[45]; const float* pb_b2 = (const float*)d_in[46];
  const float* pb_w3 = (const float*)d_in[47]; const float* pb_b3 = (const float*)d_in[48];
  float* out = (float*)d_out;

  // ---- workspace: fp32 region ----
  float* ws = (float*)d_ws;
  size_t woff = 0;
  auto alloc = [&](size_t n) { float* p = ws + woff; woff += n; return p; };
  float* output   = alloc((size_t)R_ * D_);
  float* out_prev = alloc((size_t)R_ * D_);
  float* qp       = alloc((size_t)R_ * D_);
  float* t2       = alloc((size_t)R_ * D_);
  float* offawf   = alloc((size_t)R_ * 288);  // also scores (R*80), pbout (R*4)
  float* U        = alloc((size_t)R_ * 512);  // union: qp1hid(bf)/qkv(bf)/g12(f32)/ffnhid(bf)
  float* corners0 = alloc((size_t)R_ * 4 * NBIN_);
  float* corners1 = alloc((size_t)R_ * 4 * NBIN_);
  float* refA     = alloc((size_t)R_ * 4);
  float* refB     = alloc((size_t)R_ * 4);
  float* ref_init = alloc((size_t)R_ * 4);
  float* qkvb     = alloc((size_t)NLAYERS_ * 768);
  float* offawb   = alloc((size_t)NLAYERS_ * 288);

  // ---- workspace: bf16 region ----
  short* sws = (short*)(ws + woff);
  size_t soff = 0;
  auto salloc = [&](size_t n) { short* p = sws + soff; soff += n; return p; };
  short* outbf = salloc((size_t)R_ * D_);
  short* oqbf  = salloc((size_t)R_ * D_);   // (output[+qp]) staged bf16, reused 3x/layer
  short* tbf   = salloc((size_t)R_ * D_);   // attn out, then deform out
  short* h1bf  = salloc((size_t)R_ * D_);
  short* h2bf  = salloc((size_t)R_ * D_);
  short* qp2t  = salloc((size_t)256 * 512);
  short* sqkvt = salloc((size_t)NLAYERS_ * 768 * 256);
  short* soffawt = salloc((size_t)NLAYERS_ * 288 * 256);
  short* gatet = salloc((size_t)NLAYERS_ * 512 * 512);
  short* ff1t  = salloc((size_t)NLAYERS_ * 1024 * 256);
  short* ff2t  = salloc((size_t)NLAYERS_ * 256 * 1024);
  short* bb1t  = salloc((size_t)NLAYERS_ * 256 * 256);
  short* bb2t  = salloc((size_t)NLAYERS_ * 256 * 256);
  short* bb3t  = salloc((size_t)NLAYERS_ * 132 * 256);
  short* pb1t  = salloc((size_t)256 * 256);
  short* pb2t  = salloc((size_t)256 * 256);
  short* pb3t  = salloc((size_t)4 * 256);
  short* sct   = salloc((size_t)80 * 256);
  if (ws_size < woff * sizeof(float) + soff * sizeof(short)) return;

  short* qkv    = (short*)U;
  short* qp1hid = (short*)U;
  short* ffnhid = (short*)U;
  float* g12    = U;
  float* scores = offawf;
  float* pbout  = offawf;

  float* c_prev = corners0; float* c_cur = corners1;
  float* ref_cur = refA;    float* ref_nxt = refB;

  // ---- weight prep ----
  conv_w(stream, qp_w2, qp2t, 512, 256, 1, 0);
  conv_w(stream, sa_qw, sqkvt,               256, 256, NLAYERS_, 768 * 256);
  conv_w(stream, sa_kw, sqkvt + 256 * 256,   256, 256, NLAYERS_, 768 * 256);
  conv_w(stream, sa_vw, sqkvt + 512 * 256,   256, 256, NLAYERS_, 768 * 256);
  conv_w(stream, sa_ow, bb1t, 0, 0, 0, 0);   // dummy-avoid: replaced below
  // (sa_ow conversion into its own buffer)
  // NOTE: re-issue correctly:
  // sot
  static_assert(true, "");
  short* sot = bb1t; // placeholder name fix below
  (void)sot;
  // Proper conversions:
  // we need a dedicated buffer for sa_ow; carve from remaining space:
  short* sowt = salloc((size_t)NLAYERS_ * 256 * 256);
  if (ws_size < woff * sizeof(float) + soff * sizeof(short)) return;
  conv_w(stream, sa_ow, sowt, 256, 256, NLAYERS_, 256 * 256);
  conv_w(stream, off_w, soffawt,             256, 192, NLAYERS_, 288 * 256);
  conv_w(stream, aw_w,  soffawt + 192 * 256, 256,  96, NLAYERS_, 288 * 256);
  conv_w(stream, gate_w, gatet, 512, 512, NLAYERS_, 512 * 512);
  conv_w(stream, ff1_w, ff1t, 256, 1024, NLAYERS_, 1024 * 256);
  conv_w(stream, ff2_w, ff2t, 1024, 256, NLAYERS_, 256 * 1024);
  conv_w(stream, bb_w1, bb1t, 256, 256, NLAYERS_, 256 * 256);
  conv_w(stream, bb_w2, bb2t, 256, 256, NLAYERS_, 256 * 256);
  conv_w(stream, bb_w3, bb3t, 256, 132, NLAYERS_, 132 * 256);
  conv_w(stream, pb_w1, pb1t, 256, 256, 1, 0);
  conv_w(stream, pb_w2, pb2t, 256, 256, 1, 0);
  conv_w(stream, pb_w3, pb3t, 256, 4, 1, 0);
  conv_w(stream, sc_w + (size_t)5 * D_ * NC_, sct, 256, 80, 1, 0);
  bcat_kernel<<<egrid(NLAYERS_ * 768), 256, 0, stream>>>(sa_qb, sa_kb, sa_vb, off_b, aw_b,
                                                         qkvb, offawb);

  // ---- init ----
  fill0_kernel<<<egrid(R_ * D_), 256, 0, stream>>>(out_prev, R_ * D_);
  fill0_kernel<<<egrid(R_ * 4 * NBIN_), 256, 0, stream>>>(c_prev, R_ * 4 * NBIN_);
  sigmoid_kernel<<<egrid(R_ * 4), 256, 0, stream>>>(ref_cur, ref_unact, R_ * 4);
  hipMemcpyAsync(output, target, (size_t)R_ * D_ * sizeof(float),
                 hipMemcpyDeviceToDevice, stream);
  cvtbf_kernel<<<egrid(R_ * D_ / 4), 256, 0, stream>>>(outbf, target, R_ * D_ / 4);

  for (int i = 0; i < NLAYERS_; ++i) {
    // qp = clip(mlp2(ref_pts), -10, 10)
    gemm_qp1<<<dim3(8, 75), 256, 0, stream>>>(ref_cur, qp_w1, qp_b1, qp1hid, R_, 512, 4);
    launch_bgemm(stream, qp1hid, nullptr, 0, nullptr, 0, qp2t, qp_b2,
                 nullptr, qp, nullptr, R_, D_, 512, 4);

    // ---- self attention ----
    addbf_kernel<<<egrid(R_ * D_ / 4), 256, 0, stream>>>(oqbf, output, qp, R_ * D_ / 4);
    launch_bgemm(stream, oqbf, outbf, 512, nullptr, 0, sqkvt + (size_t)i * 768 * 256,
                 qkvb + (size_t)i * 768, nullptr, nullptr, qkv, R_, 768, 256, 0);
    attn3_kernel<<<dim3(B_ * NH_ * 2), 256, 0, stream>>>(qkv, tbf);
    launch_bgemm(stream, tbf, nullptr, 0, nullptr, 0, sowt + (size_t)i * 65536,
                 sa_ob + (size_t)i * D_, nullptr, t2, nullptr, R_, D_, 256, 0);
    ln_kernel<0><<<dim3(R_), 256, 0, stream>>>(output, outbf, output, t2, nullptr,
                                               n1_g + (size_t)i * D_, n1_b + (size_t)i * D_);

    // ---- deformable cross attention ----
    addbf_kernel<<<egrid(R_ * D_ / 4), 256, 0, stream>>>(oqbf, output, qp, R_ * D_ / 4);
    launch_bgemm(stream, oqbf, nullptr, 0, nullptr, 0, soffawt + (size_t)i * 288 * 256,
                 offawb + (size_t)i * 288, nullptr, offawf, nullptr, R_, 288, 256, 0);
    deform_kernel<<<dim3(R_), 256, 0, stream>>>(memory, offawf, ref_cur, t2, tbf);

    // ---- gateway ----
    launch_bgemm(stream, outbf, nullptr, 0, tbf, 256, gatet + (size_t)i * 262144,
                 gate_b + (size_t)i * 512, nullptr, g12, nullptr, R_, 512, 512, 3);
    ln_kernel<2><<<dim3(R_), 256, 0, stream>>>(output, outbf, output, t2, g12,
                                               gn_g + (size_t)i * D_, gn_b + (size_t)i * D_);

    // ---- FFN ----
    launch_bgemm(stream, outbf, nullptr, 0, nullptr, 0, ff1t + (size_t)i * 262144,
                 ff1_b + (size_t)i * FF_, nullptr, nullptr, ffnhid, R_, FF_, 256, 1);
    launch_bgemm(stream, ffnhid, nullptr, 0, nullptr, 0, ff2t + (size_t)i * 262144,
                 ff2_b + (size_t)i * D_, nullptr, t2, nullptr, R_, D_, 1024, 0);
    ln_kernel<1><<<dim3(R_), 256, 0, stream>>>(output, outbf, output, t2, nullptr,
                                               n3_g + (size_t)i * D_, n3_b + (size_t)i * D_);

    // ---- FDR box refinement ----
    if (i == 0) {
      launch_bgemm(stream, outbf, nullptr, 0, nullptr, 0, pb1t, pb_b1, nullptr,
                   nullptr, h1bf, R_, D_, 256, 2);
      launch_bgemm(stream, h1bf, nullptr, 0, nullptr, 0, pb2t, pb_b2, nullptr,
                   nullptr, h2bf, R_, D_, 256, 2);
      launch_bgemm(stream, h2bf, nullptr, 0, nullptr, 0, pb3t, pb_b3, nullptr,
                   pbout, nullptr, R_, 4, 256, 0);
      prebb_kernel<<<egrid(R_ * 4), 256, 0, stream>>>(ref_init, pbout, ref_cur, R_ * 4);
    }
    addbf_kernel<<<egrid(R_ * D_ / 4), 256, 0, stream>>>(oqbf, output, out_prev, R_ * D_ / 4);
    launch_bgemm(stream, oqbf, nullptr, 0, nullptr, 0, bb1t + (size_t)i * 65536,
                 bb_b1 + (size_t)i * D_, nullptr, nullptr, h1bf, R_, D_, 256, 2);
    launch_bgemm(stream, h1bf, nullptr, 0, nullptr, 0, bb2t + (size_t)i * 65536,
                 bb_b2 + (size_t)i * D_, nullptr, nullptr, h2bf, R_, D_, 256, 2);
    launch_bgemm(stream, h2bf, nullptr, 0, nullptr, 0, bb3t + (size_t)i * 33792,
                 bb_b3 + (size_t)i * 4 * NBIN_, c_prev, c_cur, nullptr, R_, 4 * NBIN_, 256, 0);
    bbox_kernel<<<egrid(R_), 256, 0, stream>>>(c_cur, ref_init, ref_nxt);

    if (i == NLAYERS_ - 1) {
      launch_bgemm(stream, outbf, nullptr, 0, nullptr, 0, sct, sc_b + (size_t)5 * NC_,
                   nullptr, scores, nullptr, R_, NC_, 256, 0);
      lqe_kernel<<<dim3(R_), 64, 0, stream>>>(scores, c_cur,
                                              lqe_w1 + (size_t)5 * 20 * 64, lqe_b1 + (size_t)5 * 64,
                                              lqe_w2 + (size_t)5 * 64, lqe_b2 + (size_t)5,
                                              ref_nxt, out);
    } else {
      hipMemcpyAsync(out_prev, output, (size_t)R_ * D_ * sizeof(float),
                     hipMemcpyDeviceToDevice, stream);
      std::swap(c_prev, c_cur);
      std::swap(ref_cur, ref_nxt);
    }
  }
}

// Round 4
// 2135.946 us; speedup vs baseline: 4.0115x; 1.0670x over previous
//
#include <hip/hip_runtime.h>
#include <cstddef>
#include <cmath>
#include <utility>

#define B_ 16
#define LQ_ 300
#define D_ 256
#define NH_ 8
#define HD_ 32
#define FF_ 1024
#define NBIN_ 33
#define NC_ 80
#define SUMP_ 12
#define TOT_ (NH_*SUMP_)   // 96
#define STOT_ 8400
#define R_ (B_*LQ_)        // 4800
#define NLAYERS_ 6

typedef short bf16x8 __attribute__((ext_vector_type(8)));
typedef float f32x4  __attribute__((ext_vector_type(4)));

static __device__ __forceinline__ short f2bf(float x) {
  union { float f; unsigned u; } v; v.f = x;
  unsigned r = v.u + 0x7fffu + ((v.u >> 16) & 1u);   // RNE
  return (short)(r >> 16);
}
static __device__ __forceinline__ float bf2f(short s) {
  union { unsigned u; float f; } v; v.u = ((unsigned)(unsigned short)s) << 16; return v.f;
}

// ---------------------------------------------------------------------------
// Weight convert+transpose: W [K,N] fp32 -> Wt [N,K] bf16 at out-stride.
// ---------------------------------------------------------------------------
__launch_bounds__(256)
__global__ void wconv_kernel(const float* __restrict__ W, short* __restrict__ Wt,
                             int K, int N, size_t ostride) {
  __shared__ float t[32][33];
  const float* Wl = W + (size_t)blockIdx.z * K * N;
  short* Wtl = Wt + (size_t)blockIdx.z * ostride;
  int k0 = blockIdx.x * 32, n0 = blockIdx.y * 32;
  int tr = threadIdx.x >> 5, tc = threadIdx.x & 31;
  #pragma unroll
  for (int i = 0; i < 4; ++i) {
    int k = k0 + tr + i * 8, n = n0 + tc;
    t[tr + i * 8][tc] = (k < K && n < N) ? Wl[(size_t)k * N + n] : 0.f;
  }
  __syncthreads();
  #pragma unroll
  for (int i = 0; i < 4; ++i) {
    int n = n0 + tr + i * 8, k = k0 + tc;
    if (n < N && k < K) Wtl[(size_t)n * K + k] = f2bf(t[tc][tr + i * 8]);
  }
}

// ---------------------------------------------------------------------------
// memory fp32 [B,S,256] -> bf16 head-major [B,NH,S,32]
// ---------------------------------------------------------------------------
__launch_bounds__(256)
__global__ void memconv_kernel(const float* __restrict__ mem, short* __restrict__ mb) {
  int gs = blockIdx.x * 4 + (threadIdx.x >> 6);   // b*STOT+s
  int c  = (threadIdx.x & 63) * 4;
  int b = gs / STOT_, s = gs - b * STOT_;
  float4 v = *(const float4*)(mem + (size_t)gs * 256 + c);
  int h = c >> 5, cc = c & 31;
  short4 o; o.x = f2bf(v.x); o.y = f2bf(v.y); o.z = f2bf(v.z); o.w = f2bf(v.w);
  *(short4*)(mb + (((size_t)(b * 8 + h) * STOT_ + s) * 32) + cc) = o;
}

// ---------------------------------------------------------------------------
// Barrier-free bf16 MFMA GEMM, templated K. C = act(Asel @ Wt^T + bias [+Cadd]).
// ACT: 0 none,1 relu,2 silu,3 sigmoid,4 clip10, 5 qp-mode (Cf=clip(v),
//      Cbf=bf16(clip(v)+Cadd)).
// ---------------------------------------------------------------------------
template<int ACT, int KT>
__launch_bounds__(256)
__global__ void bgemm(const short* __restrict__ A, const short* __restrict__ A2, int N2,
                      const short* __restrict__ Acat, int KA,
                      const short* __restrict__ Wt, const float* __restrict__ bias,
                      const float* __restrict__ Cadd, float* __restrict__ Cf,
                      short* __restrict__ Cbf, int M, int N) {
  const int bm = blockIdx.y * 64, bn = blockIdx.x * 64;
  const int tid = threadIdx.x, wid = tid >> 6, lane = tid & 63;
  const int wm = (wid >> 1) * 32, wn = (wid & 1) * 32;
  const int lr = lane & 15, lq = lane >> 4;
  const short* Ab = (A2 && bn >= N2) ? A2 : A;
  const int lda = Acat ? KA : KT;
  const int ldb = KT - KA;
  const int r0 = bm + wm + lr, r1 = r0 + 16;
  const int n0 = bn + wn + lr, n1 = n0 + 16;
  const bool v0 = n0 < N, v1 = n1 < N;
  const short* w0p = Wt + (size_t)(v0 ? n0 : 0) * KT + lq * 8;
  const short* w1p = Wt + (size_t)(v1 ? n1 : 0) * KT + lq * 8;
  f32x4 acc[2][2];
  #pragma unroll
  for (int i = 0; i < 2; ++i)
    #pragma unroll
    for (int j = 0; j < 2; ++j) acc[i][j] = (f32x4){0.f, 0.f, 0.f, 0.f};

  #pragma unroll 4
  for (int k0 = 0; k0 < KT; k0 += 32) {
    const short* src; int ko, ld;
    if (Acat && k0 >= KA) { src = Acat; ko = k0 - KA; ld = ldb; }
    else                  { src = Ab;   ko = k0;      ld = lda; }
    bf16x8 a0 = *(const bf16x8*)(src + (size_t)r0 * ld + ko + lq * 8);
    bf16x8 a1 = *(const bf16x8*)(src + (size_t)r1 * ld + ko + lq * 8);
    bf16x8 w0 = *(const bf16x8*)(w0p + k0);
    bf16x8 w1 = *(const bf16x8*)(w1p + k0);
    acc[0][0] = __builtin_amdgcn_mfma_f32_16x16x32_bf16(a0, w0, acc[0][0], 0, 0, 0);
    acc[0][1] = __builtin_amdgcn_mfma_f32_16x16x32_bf16(a0, w1, acc[0][1], 0, 0, 0);
    acc[1][0] = __builtin_amdgcn_mfma_f32_16x16x32_bf16(a1, w0, acc[1][0], 0, 0, 0);
    acc[1][1] = __builtin_amdgcn_mfma_f32_16x16x32_bf16(a1, w1, acc[1][1], 0, 0, 0);
  }
  #pragma unroll
  for (int ti = 0; ti < 2; ++ti)
    #pragma unroll
    for (int tj = 0; tj < 2; ++tj) {
      int gn = bn + wn + tj * 16 + lr;
      if (gn >= N) continue;
      float bv = bias[gn];
      #pragma unroll
      for (int r = 0; r < 4; ++r) {
        int gm = bm + wm + ti * 16 + lq * 4 + r;
        size_t idx = (size_t)gm * N + gn;
        float v = acc[ti][tj][r] + bv;
        if (ACT == 5) {
          v = fminf(fmaxf(v, -10.f), 10.f);
          if (Cf) Cf[idx] = v;
          Cbf[idx] = f2bf(v + Cadd[idx]);
        } else {
          if (Cadd) v += Cadd[idx];
          if (ACT == 1) v = fmaxf(v, 0.f);
          if (ACT == 2) v = v / (1.f + __expf(-v));
          if (ACT == 3) v = 1.f / (1.f + __expf(-v));
          if (ACT == 4) v = fminf(fmaxf(v, -10.f), 10.f);
          if (Cf)  Cf[idx] = v;
          if (Cbf) Cbf[idx] = f2bf(v);
        }
      }
    }
}

// ---------------------------------------------------------------------------
// qp layer-1: direct K=4 kernel, silu, bf16 out.
// ---------------------------------------------------------------------------
__launch_bounds__(256)
__global__ void qp1_kernel(const float* __restrict__ A, const float* __restrict__ W,
                           const float* __restrict__ bias, short* __restrict__ out) {
  int i = blockIdx.x * 256 + threadIdx.x;
  if (i >= R_ * 512) return;
  int r = i >> 9, n = i & 511;
  float4 a = *(const float4*)(A + (size_t)r * 4);
  float v = bias[n] + a.x * W[n] + a.y * W[512 + n] + a.z * W[1024 + n] + a.w * W[1536 + n];
  v = v / (1.f + __expf(-v));
  out[i] = f2bf(v);
}

// ---------------------------------------------------------------------------
// LayerNorm (fused add/gate) over D=256.
//  MODE 0: x=a+b      (+ optional out2bf = bf16(v + add2))
//  MODE 1: x=clip(a+b); out2bf = bf16(v + prevbuf_old); prevbuf = v
//  MODE 2: x=g1*a+g2*b
// ---------------------------------------------------------------------------
template<int MODE>
__launch_bounds__(256)
__global__ void ln_kernel(float* __restrict__ out, short* __restrict__ outbf,
                          const float* __restrict__ a, const float* __restrict__ b,
                          const float* __restrict__ g12,
                          const float* __restrict__ gamma, const float* __restrict__ beta,
                          const float* __restrict__ add2, short* __restrict__ out2bf,
                          float* __restrict__ prevbuf) {
  const int row = blockIdx.x, c = threadIdx.x;
  const size_t off = (size_t)row * D_ + c;
  float x;
  if (MODE == 0) x = a[off] + b[off];
  else if (MODE == 1) { x = a[off] + b[off]; x = fminf(fmaxf(x, -65504.f), 65504.f); }
  else {
    float g1 = g12[(size_t)row * 2 * D_ + c];
    float g2 = g12[(size_t)row * 2 * D_ + D_ + c];
    x = g1 * a[off] + g2 * b[off];
  }
  __shared__ float red[8];
  float s = x;
  #pragma unroll
  for (int o = 32; o; o >>= 1) s += __shfl_down(s, o);
  if ((c & 63) == 0) red[c >> 6] = s;
  __syncthreads();
  float mu = (red[0] + red[1] + red[2] + red[3]) * (1.f / D_);
  float dd = x - mu;
  float s2 = dd * dd;
  #pragma unroll
  for (int o = 32; o; o >>= 1) s2 += __shfl_down(s2, o);
  if ((c & 63) == 0) red[4 + (c >> 6)] = s2;
  __syncthreads();
  float var = (red[4] + red[5] + red[6] + red[7]) * (1.f / D_);
  float v = dd * rsqrtf(var + 1e-5f) * gamma[c] + beta[c];
  out[off] = v;
  if (outbf) outbf[off] = f2bf(v);
  if (MODE == 1) {
    float po = prevbuf[off];
    out2bf[off] = f2bf(v + po);
    prevbuf[off] = v;
  } else if (add2) {
    out2bf[off] = f2bf(v + add2[off]);
  }
}

// ---------------------------------------------------------------------------
// MFMA self-attention (as R2). Block per (b,h,half).
// ---------------------------------------------------------------------------
__launch_bounds__(256)
__global__ void attn3_kernel(const short* __restrict__ qkv, short* __restrict__ O) {
  __shared__ short Kb[304][40];
  __shared__ short Vt[32][328];
  __shared__ short Pw[4][16][328];
  const int half = blockIdx.x & 1, bh = blockIdx.x >> 1;
  const int h = bh & 7, b = bh >> 3;
  const int tid = threadIdx.x;
  const short* QKVb = qkv + (size_t)b * LQ_ * 768;
  for (int idx = tid; idx < 304 * 4; idx += 256) {
    int row = idx >> 2, seg = (idx & 3) * 8;
    bf16x8 v = (row < 300) ? *(const bf16x8*)(QKVb + (size_t)row * 768 + 256 + h * 32 + seg)
                           : (bf16x8){0,0,0,0,0,0,0,0};
    *(bf16x8*)&Kb[row][seg] = v;
  }
  for (int idx = tid; idx < 300 * 4; idx += 256) {
    int row = idx >> 2, seg = (idx & 3) * 8;
    bf16x8 v = *(const bf16x8*)(QKVb + (size_t)row * 768 + 512 + h * 32 + seg);
    #pragma unroll
    for (int j = 0; j < 8; ++j) Vt[seg + j][row] = v[j];
  }
  for (int idx = tid; idx < 32 * 20; idx += 256) Vt[idx / 20][300 + idx % 20] = 0;
  for (int idx = tid; idx < 4 * 16 * 16; idx += 256)
    Pw[idx >> 8][(idx >> 4) & 15][304 + (idx & 15)] = 0;
  __syncthreads();

  const int wid = tid >> 6, lane = tid & 63;
  const int lr = lane & 15, lq = lane >> 4;
  short (*Pl)[328] = Pw[wid];
  const float scale = 0.17677669529663687f;

  for (int qt = wid; qt < 10; qt += 4) {
    const int q0 = half * 150 + qt * 16;
    int qrow = q0 + lr; if (qrow > 299) qrow = 299;
    bf16x8 af_q = *(const bf16x8*)(QKVb + (size_t)qrow * 768 + h * 32 + lq * 8);
    f32x4 s[19];
    #pragma unroll
    for (int t = 0; t < 19; ++t) {
      bf16x8 bk = *(const bf16x8*)&Kb[t * 16 + lr][lq * 8];
      s[t] = __builtin_amdgcn_mfma_f32_16x16x32_bf16(af_q, bk, (f32x4){0.f,0.f,0.f,0.f}, 0, 0, 0);
    }
    #pragma unroll
    for (int t = 0; t < 19; ++t)
      #pragma unroll
      for (int r = 0; r < 4; ++r) s[t][r] *= scale;
    if (lr >= 12) { s[18][0] = s[18][1] = s[18][2] = s[18][3] = -1e30f; }
    float l[4];
    #pragma unroll
    for (int r = 0; r < 4; ++r) {
      float mm = -1e30f;
      #pragma unroll
      for (int t = 0; t < 19; ++t) mm = fmaxf(mm, s[t][r]);
      #pragma unroll
      for (int x = 1; x < 16; x <<= 1) mm = fmaxf(mm, __shfl_xor(mm, x));
      float ll = 0.f;
      #pragma unroll
      for (int t = 0; t < 19; ++t) { float p = __expf(s[t][r] - mm); s[t][r] = p; ll += p; }
      #pragma unroll
      for (int x = 1; x < 16; x <<= 1) ll += __shfl_xor(ll, x);
      l[r] = ll;
    }
    #pragma unroll
    for (int t = 0; t < 19; ++t)
      #pragma unroll
      for (int r = 0; r < 4; ++r) Pl[lq * 4 + r][t * 16 + lr] = f2bf(s[t][r]);
    f32x4 o0 = (f32x4){0.f,0.f,0.f,0.f}, o1 = (f32x4){0.f,0.f,0.f,0.f};
    #pragma unroll
    for (int c = 0; c < 10; ++c) {
      bf16x8 ap = *(const bf16x8*)&Pl[lr][c * 32 + lq * 8];
      bf16x8 v0 = *(const bf16x8*)&Vt[lr][c * 32 + lq * 8];
      bf16x8 v1 = *(const bf16x8*)&Vt[16 + lr][c * 32 + lq * 8];
      o0 = __builtin_amdgcn_mfma_f32_16x16x32_bf16(ap, v0, o0, 0, 0, 0);
      o1 = __builtin_amdgcn_mfma_f32_16x16x32_bf16(ap, v1, o1, 0, 0, 0);
    }
    #pragma unroll
    for (int r = 0; r < 4; ++r) {
      int q = q0 + lq * 4 + r;
      if (q >= 300) continue;
      float inv = 1.f / l[r];
      size_t ob = (size_t)(b * LQ_ + q) * 256 + h * 32;
      O[ob + lr]      = f2bf(o0[r] * inv);
      O[ob + 16 + lr] = f2bf(o1[r] * inv);
    }
  }
}

// ---------------------------------------------------------------------------
// Deformable sampling. BF16MEM: mem is bf16 head-major [B,NH,S,32];
// else fp32 [B,S,256]. XCD-swizzled block->row mapping.
// ---------------------------------------------------------------------------
template<int BF16MEM>
__launch_bounds__(256)
__global__ void deform_kernel(const void* __restrict__ memv, const float* __restrict__ offaw,
                              const float* __restrict__ refp,
                              float* __restrict__ t2, short* __restrict__ t2bf) {
  const int bi = blockIdx.x;
  const int row = (bi & 7) * 600 + (bi >> 3);   // XCD locality swizzle
  const int b = row / LQ_;
  const int tid = threadIdx.x;
  const int h = tid >> 5, c = tid & 31;
  const float rx = refp[row * 4 + 0], ry = refp[row * 4 + 1];
  const float rw = refp[row * 4 + 2], rh = refp[row * 4 + 3];
  const float* awp = offaw + (size_t)row * 288 + 192 + h * SUMP_;
  float wv[SUMP_];
  float wmax = -1e30f;
  #pragma unroll
  for (int p = 0; p < SUMP_; ++p) { wv[p] = awp[p]; wmax = fmaxf(wmax, wv[p]); }
  float wsum = 0.f;
  #pragma unroll
  for (int p = 0; p < SUMP_; ++p) { wv[p] = __expf(wv[p] - wmax); wsum += wv[p]; }
  const float winv = 1.f / wsum;
  const float* op = offaw + (size_t)row * 288 + h * (SUMP_ * 2);
  const short* mb16 = BF16MEM ? ((const short*)memv + ((size_t)(b * 8 + h) * STOT_) * 32 + c) : nullptr;
  const float* mb32 = BF16MEM ? nullptr : ((const float*)memv + (size_t)b * STOT_ * 256 + h * 32 + c);
  float acc = 0.f;
  #pragma unroll
  for (int p = 0; p < SUMP_; ++p) {
    const int lvl = p >> 2;
    const int Wl = (lvl == 0) ? 80 : ((lvl == 1) ? 40 : 20);
    const int Hl = Wl;
    const int s0 = (lvl == 0) ? 0 : ((lvl == 1) ? 6400 : 8000);
    float lx = rx + op[2 * p]     * 0.125f * rw;
    float ly = ry + op[2 * p + 1] * 0.125f * rh;
    float x = lx * Wl - 0.5f, y = ly * Hl - 0.5f;
    float xf = floorf(x), yf = floorf(y);
    int x0 = (int)xf, y0 = (int)yf;
    float wx = x - xf, wy = y - yf;
    float v = 0.f;
    bool xv0 = (x0 >= 0) && (x0 < Wl), xv1 = (x0 + 1 >= 0) && (x0 + 1 < Wl);
    bool yv0 = (y0 >= 0) && (y0 < Hl), yv1 = (y0 + 1 >= 0) && (y0 + 1 < Hl);
    if (BF16MEM) {
      const short* mb = mb16 + (size_t)s0 * 32;
      if (yv0) {
        if (xv0) v += (1.f - wx) * (1.f - wy) * bf2f(mb[(size_t)(y0 * Wl + x0) * 32]);
        if (xv1) v += wx * (1.f - wy) * bf2f(mb[(size_t)(y0 * Wl + x0 + 1) * 32]);
      }
      if (yv1) {
        if (xv0) v += (1.f - wx) * wy * bf2f(mb[(size_t)((y0 + 1) * Wl + x0) * 32]);
        if (xv1) v += wx * wy * bf2f(mb[(size_t)((y0 + 1) * Wl + x0 + 1) * 32]);
      }
    } else {
      const float* mb = mb32 + (size_t)s0 * 256;
      if (yv0) {
        if (xv0) v += (1.f - wx) * (1.f - wy) * mb[(size_t)(y0 * Wl + x0) * 256];
        if (xv1) v += wx * (1.f - wy) * mb[(size_t)(y0 * Wl + x0 + 1) * 256];
      }
      if (yv1) {
        if (xv0) v += (1.f - wx) * wy * mb[(size_t)((y0 + 1) * Wl + x0) * 256];
        if (xv1) v += wx * wy * mb[(size_t)((y0 + 1) * Wl + x0 + 1) * 256];
      }
    }
    acc += wv[p] * winv * v;
  }
  size_t off = (size_t)row * D_ + h * HD_ + c;
  t2[off] = acc;
  t2bf[off] = f2bf(acc);
}

// ---------------------------------------------------------------------------
// corners -> dist -> distance2bbox
// ---------------------------------------------------------------------------
__launch_bounds__(256)
__global__ void bbox_kernel(const float* __restrict__ corners, const float* __restrict__ refi,
                            float* __restrict__ inter) {
  int row = blockIdx.x * blockDim.x + threadIdx.x;
  if (row >= R_) return;
  float proj[NBIN_];
  proj[0] = -4.f; proj[16] = 0.f; proj[32] = 4.f;
  const float step = powf(3.f, 1.f / 15.f);
  float pw = 1.f;
  for (int i = 1; i <= 15; ++i) { pw *= step; proj[16 + i] = pw - 1.f; proj[16 - i] = 1.f - pw; }
  float dist[4];
  for (int s = 0; s < 4; ++s) {
    const float* cp = corners + (size_t)row * (4 * NBIN_) + s * NBIN_;
    float m = -1e30f;
    for (int j = 0; j < NBIN_; ++j) m = fmaxf(m, cp[j]);
    float sum = 0.f, dot = 0.f;
    for (int j = 0; j < NBIN_; ++j) { float e = __expf(cp[j] - m); sum += e; dot += e * proj[j]; }
    dist[s] = dot / sum;
  }
  float px = refi[row * 4], py = refi[row * 4 + 1];
  float qw = refi[row * 4 + 2] * 0.25f, qh = refi[row * 4 + 3] * 0.25f;
  float x1 = px - (2.f + dist[0]) * qw, y1 = py - (2.f + dist[1]) * qh;
  float x2 = px + (2.f + dist[2]) * qw, y2 = py + (2.f + dist[3]) * qh;
  inter[row * 4 + 0] = (x1 + x2) * 0.5f;
  inter[row * 4 + 1] = (y1 + y2) * 0.5f;
  inter[row * 4 + 2] = x2 - x1;
  inter[row * 4 + 3] = y2 - y1;
}

// ---------------------------------------------------------------------------
// LQE head + final output assembly.
// ---------------------------------------------------------------------------
__launch_bounds__(64)
__global__ void lqe_kernel(const float* __restrict__ scores, const float* __restrict__ corners,
                           const float* __restrict__ w1, const float* __restrict__ b1,
                           const float* __restrict__ w2, const float* __restrict__ b2,
                           const float* __restrict__ inter, float* __restrict__ out) {
  const int row = blockIdx.x;
  const int tid = threadIdx.x;
  __shared__ float stat[20];
  __shared__ float lqe_s;
  if (tid < 4) {
    const float* cp = corners + (size_t)row * (4 * NBIN_) + tid * NBIN_;
    float m = -1e30f;
    for (int j = 0; j < NBIN_; ++j) m = fmaxf(m, cp[j]);
    float e[NBIN_]; float sum = 0.f;
    for (int j = 0; j < NBIN_; ++j) { e[j] = __expf(cp[j] - m); sum += e[j]; }
    float inv = 1.f / sum;
    float mean = 0.f;
    for (int t = 0; t < 4; ++t) {
      int bi = 0; float best = -1.f;
      for (int j = 0; j < NBIN_; ++j) if (e[j] > best) { best = e[j]; bi = j; }
      e[bi] = -2.f;
      float v = best * inv;
      stat[tid * 5 + t] = v; mean += v;
    }
    stat[tid * 5 + 4] = mean * 0.25f;
  }
  __syncthreads();
  float s = b1[tid];
  #pragma unroll
  for (int i = 0; i < 20; ++i) s += stat[i] * w1[i * 64 + tid];
  float hv = s / (1.f + __expf(-s));
  float v = hv * w2[tid];
  #pragma unroll
  for (int o = 32; o; o >>= 1) v += __shfl_down(v, o);
  if (tid == 0) lqe_s = v + b2[0];
  __syncthreads();
  if (tid < 4) out[(size_t)row * 84 + tid] = inter[row * 4 + tid];
  for (int c = tid; c < NC_; c += 64)
    out[(size_t)row * 84 + 4 + c] = scores[(size_t)row * NC_ + c] + lqe_s;
}

// ---------------------------------------------------------------------------
// small elementwise kernels
// ---------------------------------------------------------------------------
__global__ void fill0_kernel(float* __restrict__ p, int n) {
  int i = blockIdx.x * 256 + threadIdx.x; if (i < n) p[i] = 0.f;
}
__global__ void sigmoid_kernel(float* __restrict__ d, const float* __restrict__ s, int n) {
  int i = blockIdx.x * 256 + threadIdx.x; if (i < n) d[i] = 1.f / (1.f + __expf(-s[i]));
}
__global__ void prebb_kernel(float* __restrict__ d, const float* __restrict__ pre,
                             const float* __restrict__ refp, int n) {
  int i = blockIdx.x * 256 + threadIdx.x;
  if (i < n) {
    float x = refp[i];
    x = fminf(fmaxf(x, 1e-5f), 1.f - 1e-5f);
    float is = logf(x) - log1pf(-x);
    d[i] = 1.f / (1.f + __expf(-(pre[i] + is)));
  }
}
__global__ void initcvt_kernel(float* __restrict__ o, short* __restrict__ ob,
                               const float* __restrict__ t, int n4) {
  int i = blockIdx.x * 256 + threadIdx.x;
  if (i < n4) {
    float4 v = ((const float4*)t)[i];
    ((float4*)o)[i] = v;
    short4 s; s.x = f2bf(v.x); s.y = f2bf(v.y); s.z = f2bf(v.z); s.w = f2bf(v.w);
    ((short4*)ob)[i] = s;
  }
}
__global__ void bcat_kernel(const float* __restrict__ qb, const float* __restrict__ kb,
                            const float* __restrict__ vb, const float* __restrict__ ob,
                            const float* __restrict__ ab, float* __restrict__ qkvb,
                            float* __restrict__ offawb) {
  int i = blockIdx.x * 256 + threadIdx.x;
  if (i < NLAYERS_ * 768) {
    int l = i / 768, c = i % 768;
    qkvb[i] = (c < 256) ? qb[l * 256 + c] : (c < 512) ? kb[l * 256 + c - 256]
                        : vb[l * 256 + c - 512];
  }
  if (i < NLAYERS_ * 288) {
    int l = i / 288, c = i % 288;
    offawb[i] = (c < 192) ? ob[l * 192 + c] : ab[l * 96 + c - 192];
  }
}

// ---------------------------------------------------------------------------
// host orchestration
// ---------------------------------------------------------------------------
template<int KT>
static void launch_bgemm_k(hipStream_t st, const short* A, const short* A2, int N2,
                           const short* Acat, int KA, const short* Wt, const float* bias,
                           const float* Cadd, float* Cf, short* Cbf, int M, int N, int act) {
  dim3 g((N + 63) / 64, M / 64), blk(256);
  switch (act) {
    case 0: bgemm<0,KT><<<g, blk, 0, st>>>(A, A2, N2, Acat, KA, Wt, bias, Cadd, Cf, Cbf, M, N); break;
    case 1: bgemm<1,KT><<<g, blk, 0, st>>>(A, A2, N2, Acat, KA, Wt, bias, Cadd, Cf, Cbf, M, N); break;
    case 2: bgemm<2,KT><<<g, blk, 0, st>>>(A, A2, N2, Acat, KA, Wt, bias, Cadd, Cf, Cbf, M, N); break;
    case 3: bgemm<3,KT><<<g, blk, 0, st>>>(A, A2, N2, Acat, KA, Wt, bias, Cadd, Cf, Cbf, M, N); break;
    case 4: bgemm<4,KT><<<g, blk, 0, st>>>(A, A2, N2, Acat, KA, Wt, bias, Cadd, Cf, Cbf, M, N); break;
    case 5: bgemm<5,KT><<<g, blk, 0, st>>>(A, A2, N2, Acat, KA, Wt, bias, Cadd, Cf, Cbf, M, N); break;
  }
}
static void launch_bgemm(hipStream_t st, const short* A, const short* A2, int N2,
                         const short* Acat, int KA, const short* Wt, const float* bias,
                         const float* Cadd, float* Cf, short* Cbf,
                         int M, int N, int K, int act) {
  if (K == 256)      launch_bgemm_k<256>(st, A, A2, N2, Acat, KA, Wt, bias, Cadd, Cf, Cbf, M, N, act);
  else if (K == 512) launch_bgemm_k<512>(st, A, A2, N2, Acat, KA, Wt, bias, Cadd, Cf, Cbf, M, N, act);
  else               launch_bgemm_k<1024>(st, A, A2, N2, Acat, KA, Wt, bias, Cadd, Cf, Cbf, M, N, act);
}

static void conv_w(hipStream_t st, const float* W, short* Wt, int K, int N, int L,
                   size_t ostride) {
  dim3 g((K + 31) / 32, (N + 31) / 32, L);
  wconv_kernel<<<g, 256, 0, st>>>(W, Wt, K, N, ostride);
}

static inline dim3 egrid(int n) { return dim3((n + 255) / 256); }

extern "C" void kernel_launch(void* const* d_in, const int* in_sizes, int n_in,
                              void* d_out, int out_size, void* d_ws, size_t ws_size,
                              hipStream_t stream) {
  const float* target     = (const float*)d_in[0];
  const float* ref_unact  = (const float*)d_in[1];
  const float* memory     = (const float*)d_in[2];
  const float* sa_qw = (const float*)d_in[3];  const float* sa_qb = (const float*)d_in[4];
  const float* sa_kw = (const float*)d_in[5];  const float* sa_kb = (const float*)d_in[6];
  const float* sa_vw = (const float*)d_in[7];  const float* sa_vb = (const float*)d_in[8];
  const float* sa_ow = (const float*)d_in[9];  const float* sa_ob = (const float*)d_in[10];
  const float* n1_g  = (const float*)d_in[11]; const float* n1_b  = (const float*)d_in[12];
  const float* off_w = (const float*)d_in[13]; const float* off_b = (const float*)d_in[14];
  const float* aw_w  = (const float*)d_in[15]; const float* aw_b  = (const float*)d_in[16];
  const float* gate_w= (const float*)d_in[17]; const float* gate_b= (const float*)d_in[18];
  const float* gn_g  = (const float*)d_in[19]; const float* gn_b  = (const float*)d_in[20];
  const float* ff1_w = (const float*)d_in[21]; const float* ff1_b = (const float*)d_in[22];
  const float* ff2_w = (const float*)d_in[23]; const float* ff2_b = (const float*)d_in[24];
  const float* n3_g  = (const float*)d_in[25]; const float* n3_b  = (const float*)d_in[26];
  const float* bb_w1 = (const float*)d_in[27]; const float* bb_b1 = (const float*)d_in[28];
  const float* bb_w2 = (const float*)d_in[29]; const float* bb_b2 = (const float*)d_in[30];
  const float* bb_w3 = (const float*)d_in[31]; const float* bb_b3 = (const float*)d_in[32];
  const float* sc_w  = (const float*)d_in[33]; const float* sc_b  = (const float*)d_in[34];
  const float* lqe_w1= (const float*)d_in[35]; const float* lqe_b1= (const float*)d_in[36];
  const float* lqe_w2= (const float*)d_in[37]; const float* lqe_b2= (const float*)d_in[38];
  const float* qp_w1 = (const float*)d_in[39]; const float* qp_b1 = (const float*)d_in[40];
  const float* qp_w2 = (const float*)d_in[41]; const float* qp_b2 = (const float*)d_in[42];
  const float* pb_w1 = (const float*)d_in[43]; const float* pb_b1 = (const float*)d_in[44];
  const float* pb_w2 = (const float*)d_in[45]; const float* pb_b2 = (const float*)d_in[46];
  const float* pb_w3 = (const float*)d_in[47]; const float* pb_b3 = (const float*)d_in[48];
  float* out = (float*)d_out;

  // ---- workspace: fp32 region ----
  float* ws = (float*)d_ws;
  size_t woff = 0;
  auto alloc = [&](size_t n) { float* p = ws + woff; woff += n; return p; };
  float* output   = alloc((size_t)R_ * D_);
  float* out_prev = alloc((size_t)R_ * D_);
  float* qp       = alloc((size_t)R_ * D_);
  float* t2       = alloc((size_t)R_ * D_);
  float* offawf   = alloc((size_t)R_ * 288);  // also scores, pbout
  float* U        = alloc((size_t)R_ * 512);  // qp1hid(bf)/qkv(bf)/g12(f32)/ffnhid(bf)
  float* corners0 = alloc((size_t)R_ * 4 * NBIN_);
  float* corners1 = alloc((size_t)R_ * 4 * NBIN_);
  float* refA     = alloc((size_t)R_ * 4);
  float* refB     = alloc((size_t)R_ * 4);
  float* ref_init = alloc((size_t)R_ * 4);
  float* qkvb     = alloc((size_t)NLAYERS_ * 768);
  float* offawb   = alloc((size_t)NLAYERS_ * 288);

  // ---- workspace: bf16 region ----
  short* sws = (short*)(ws + woff);
  size_t soff = 0;
  auto salloc = [&](size_t n) { short* p = sws + soff; soff += n; return p; };
  short* outbf = salloc((size_t)R_ * D_);
  short* oqbf  = salloc((size_t)R_ * D_);   // fused-add bf16 staging, reused 3x/layer
  short* tbf   = salloc((size_t)R_ * D_);
  short* h1bf  = salloc((size_t)R_ * D_);
  short* h2bf  = salloc((size_t)R_ * D_);
  short* qp2t  = salloc((size_t)256 * 512);
  short* sqkvt = salloc((size_t)NLAYERS_ * 768 * 256);
  short* sowt  = salloc((size_t)NLAYERS_ * 256 * 256);
  short* soffawt = salloc((size_t)NLAYERS_ * 288 * 256);
  short* gatet = salloc((size_t)NLAYERS_ * 512 * 512);
  short* ff1t  = salloc((size_t)NLAYERS_ * 1024 * 256);
  short* ff2t  = salloc((size_t)NLAYERS_ * 256 * 1024);
  short* bb1t  = salloc((size_t)NLAYERS_ * 256 * 256);
  short* bb2t  = salloc((size_t)NLAYERS_ * 256 * 256);
  short* bb3t  = salloc((size_t)NLAYERS_ * 132 * 256);
  short* pb1t  = salloc((size_t)256 * 256);
  short* pb2t  = salloc((size_t)256 * 256);
  short* pb3t  = salloc((size_t)4 * 256);
  short* sct   = salloc((size_t)80 * 256);
  size_t base_bytes = woff * sizeof(float) + soff * sizeof(short);
  if (ws_size < base_bytes) return;
  // optional bf16 head-major memory copy
  const size_t memn = (size_t)B_ * STOT_ * 256;
  bool bf16mem = (ws_size >= base_bytes + memn * sizeof(short));
  short* membf = sws + soff;   // only valid if bf16mem

  short* qkv    = (short*)U;
  short* qp1hid = (short*)U;
  short* ffnhid = (short*)U;
  float* g12    = U;
  float* scores = offawf;
  float* pbout  = offawf;

  float* c_prev = corners0; float* c_cur = corners1;
  float* ref_cur = refA;    float* ref_nxt = refB;

  // ---- weight prep ----
  conv_w(stream, qp_w2, qp2t, 512, 256, 1, 0);
  conv_w(stream, sa_qw, sqkvt,               256, 256, NLAYERS_, 768 * 256);
  conv_w(stream, sa_kw, sqkvt + 256 * 256,   256, 256, NLAYERS_, 768 * 256);
  conv_w(stream, sa_vw, sqkvt + 512 * 256,   256, 256, NLAYERS_, 768 * 256);
  conv_w(stream, sa_ow, sowt, 256, 256, NLAYERS_, 256 * 256);
  conv_w(stream, off_w, soffawt,             256, 192, NLAYERS_, 288 * 256);
  conv_w(stream, aw_w,  soffawt + 192 * 256, 256,  96, NLAYERS_, 288 * 256);
  conv_w(stream, gate_w, gatet, 512, 512, NLAYERS_, 512 * 512);
  conv_w(stream, ff1_w, ff1t, 256, 1024, NLAYERS_, 1024 * 256);
  conv_w(stream, ff2_w, ff2t, 1024, 256, NLAYERS_, 256 * 1024);
  conv_w(stream, bb_w1, bb1t, 256, 256, NLAYERS_, 256 * 256);
  conv_w(stream, bb_w2, bb2t, 256, 256, NLAYERS_, 256 * 256);
  conv_w(stream, bb_w3, bb3t, 256, 132, NLAYERS_, 132 * 256);
  conv_w(stream, pb_w1, pb1t, 256, 256, 1, 0);
  conv_w(stream, pb_w2, pb2t, 256, 256, 1, 0);
  conv_w(stream, pb_w3, pb3t, 256, 4, 1, 0);
  conv_w(stream, sc_w + (size_t)5 * D_ * NC_, sct, 256, 80, 1, 0);
  bcat_kernel<<<egrid(NLAYERS_ * 768), 256, 0, stream>>>(sa_qb, sa_kb, sa_vb, off_b, aw_b,
                                                         qkvb, offawb);
  if (bf16mem)
    memconv_kernel<<<dim3(B_ * STOT_ / 4), 256, 0, stream>>>(memory, membf);

  // ---- init ----
  fill0_kernel<<<egrid(R_ * D_), 256, 0, stream>>>(out_prev, R_ * D_);
  fill0_kernel<<<egrid(R_ * 4 * NBIN_), 256, 0, stream>>>(c_prev, R_ * 4 * NBIN_);
  sigmoid_kernel<<<egrid(R_ * 4), 256, 0, stream>>>(ref_cur, ref_unact, R_ * 4);
  initcvt_kernel<<<egrid(R_ * D_ / 4), 256, 0, stream>>>(output, outbf, target, R_ * D_ / 4);

  for (int i = 0; i < NLAYERS_; ++i) {
    // qp = clip(mlp2(ref_pts)); oqbf = bf16(output + qp) fused in epilogue
    qp1_kernel<<<egrid(R_ * 512), 256, 0, stream>>>(ref_cur, qp_w1, qp_b1, qp1hid);
    launch_bgemm(stream, qp1hid, nullptr, 0, nullptr, 0, qp2t, qp_b2,
                 /*Cadd=*/output, /*Cf=*/qp, /*Cbf=*/oqbf, R_, D_, 512, 5);

    // ---- self attention ----
    launch_bgemm(stream, oqbf, outbf, 512, nullptr, 0, sqkvt + (size_t)i * 768 * 256,
                 qkvb + (size_t)i * 768, nullptr, nullptr, qkv, R_, 768, 256, 0);
    attn3_kernel<<<dim3(B_ * NH_ * 2), 256, 0, stream>>>(qkv, tbf);
    launch_bgemm(stream, tbf, nullptr, 0, nullptr, 0, sowt + (size_t)i * 65536,
                 sa_ob + (size_t)i * D_, nullptr, t2, nullptr, R_, D_, 256, 0);
    ln_kernel<0><<<dim3(R_), 256, 0, stream>>>(output, outbf, output, t2, nullptr,
                                               n1_g + (size_t)i * D_, n1_b + (size_t)i * D_,
                                               qp, oqbf, nullptr);

    // ---- deformable cross attention ----
    launch_bgemm(stream, oqbf, nullptr, 0, nullptr, 0, soffawt + (size_t)i * 288 * 256,
                 offawb + (size_t)i * 288, nullptr, offawf, nullptr, R_, 288, 256, 0);
    if (bf16mem)
      deform_kernel<1><<<dim3(R_), 256, 0, stream>>>(membf, offawf, ref_cur, t2, tbf);
    else
      deform_kernel<0><<<dim3(R_), 256, 0, stream>>>(memory, offawf, ref_cur, t2, tbf);

    // ---- gateway ----
    launch_bgemm(stream, outbf, nullptr, 0, tbf, 256, gatet + (size_t)i * 262144,
                 gate_b + (size_t)i * 512, nullptr, g12, nullptr, R_, 512, 512, 3);
    ln_kernel<2><<<dim3(R_), 256, 0, stream>>>(output, outbf, output, t2, g12,
                                               gn_g + (size_t)i * D_, gn_b + (size_t)i * D_,
                                               nullptr, nullptr, nullptr);

    // ---- FFN ----
    launch_bgemm(stream, outbf, nullptr, 0, nullptr, 0, ff1t + (size_t)i * 262144,
                 ff1_b + (size_t)i * FF_, nullptr, nullptr, ffnhid, R_, FF_, 256, 1);
    launch_bgemm(stream, ffnhid, nullptr, 0, nullptr, 0, ff2t + (size_t)i * 262144,
                 ff2_b + (size_t)i * D_, nullptr, t2, nullptr, R_, D_, 1024, 0);
    // ln<1>: output, outbf; oqbf = bf16(v + out_prev_old); out_prev = v
    ln_kernel<1><<<dim3(R_), 256, 0, stream>>>(output, outbf, output, t2, nullptr,
                                               n3_g + (size_t)i * D_, n3_b + (size_t)i * D_,
                                               nullptr, oqbf, out_prev);

    // ---- FDR box refinement ----
    if (i == 0) {
      launch_bgemm(stream, outbf, nullptr, 0, nullptr, 0, pb1t, pb_b1, nullptr,
                   nullptr, h1bf, R_, D_, 256, 2);
      launch_bgemm(stream, h1bf, nullptr, 0, nullptr, 0, pb2t, pb_b2, nullptr,
                   nullptr, h2bf, R_, D_, 256, 2);
      launch_bgemm(stream, h2bf, nullptr, 0, nullptr, 0, pb3t, pb_b3, nullptr,
                   pbout, nullptr, R_, 4, 256, 0);
      prebb_kernel<<<egrid(R_ * 4), 256, 0, stream>>>(ref_init, pbout, ref_cur, R_ * 4);
    }
    launch_bgemm(stream, oqbf, nullptr, 0, nullptr, 0, bb1t + (size_t)i * 65536,
                 bb_b1 + (size_t)i * D_, nullptr, nullptr, h1bf, R_, D_, 256, 2);
    launch_bgemm(stream, h1bf, nullptr, 0, nullptr, 0, bb2t + (size_t)i * 65536,
                 bb_b2 + (size_t)i * D_, nullptr, nullptr, h2bf, R_, D_, 256, 2);
    launch_bgemm(stream, h2bf, nullptr, 0, nullptr, 0, bb3t + (size_t)i * 33792,
                 bb_b3 + (size_t)i * 4 * NBIN_, c_prev, c_cur, nullptr, R_, 4 * NBIN_, 256, 0);
    bbox_kernel<<<egrid(R_), 256, 0, stream>>>(c_cur, ref_init, ref_nxt);

    if (i == NLAYERS_ - 1) {
      launch_bgemm(stream, outbf, nullptr, 0, nullptr, 0, sct, sc_b + (size_t)5 * NC_,
                   nullptr, scores, nullptr, R_, NC_, 256, 0);
      lqe_kernel<<<dim3(R_), 64, 0, stream>>>(scores, c_cur,
                                              lqe_w1 + (size_t)5 * 20 * 64, lqe_b1 + (size_t)5 * 64,
                                              lqe_w2 + (size_t)5 * 64, lqe_b2 + (size_t)5,
                                              ref_nxt, out);
    } else {
      std::swap(c_prev, c_cur);
      std::swap(ref_cur, ref_nxt);
    }
  }
}